// Round 15
// baseline (719.261 us; speedup 1.0000x reference)
//
#include <hip/hip_runtime.h>
#include <hip/hip_bf16.h>
#include <cmath>

#define BB 32
#define SS 256
#define DD 1024
#define EE 256
#define FDIM 2048
#define HH 512
#define KOUT6 (6 * 1024)
#define NROW (BB * SS)          // 8192 rows per side
#define NROW2 (2 * NROW)        // 16384 combined
#define SIMSZ ((size_t)BB * SS * SS)

static constexpr float SCALE = 1.0f / 32.0f;   // 1/sqrt(1024)
static constexpr float EPSF  = 1e-13f;

typedef __attribute__((ext_vector_type(8))) short bf16x8;
typedef __attribute__((ext_vector_type(4))) float f32x4;

__device__ inline float4 ld4(const float* p) { return *(const float4*)p; }
__device__ inline ushort f2b(float f) {
    uint x = __float_as_uint(f);
    x += 0x7fffu + ((x >> 16) & 1u);      // round-to-nearest-even
    return (ushort)(x >> 16);
}
__device__ inline float b2f(ushort u) { return __uint_as_float(((uint)u) << 16); }
__device__ inline bf16x8 cvt8(const float* v) {
    bf16x8 r;
#pragma unroll
    for (int j = 0; j < 8; ++j) r[j] = (short)f2b(v[j]);
    return r;
}
__device__ inline void b2f8(bf16x8 v, float* o) {
#pragma unroll
    for (int j = 0; j < 8; ++j) o[j] = b2f((ushort)v[j]);
}

// async global->LDS, 16B/lane; LDS dest = wave-uniform base + lane*16
typedef __attribute__((address_space(1))) const uchar gas_t;
typedef __attribute__((address_space(3))) uchar las_t;
__device__ inline void gll16(const ushort* g, ushort* l) {
    __builtin_amdgcn_global_load_lds((gas_t*)g, (las_t*)l, 16, 0, 0);
}

// XCD-chunked swizzle (grid total must be %8==0)
__device__ inline int swz_orig_2d() {
    const int n   = blockIdx.y * gridDim.x + blockIdx.x;
    const int tot = gridDim.x * gridDim.y;
    return (n & 7) * (tot >> 3) + (n >> 3);
}
__device__ inline int swz_orig_3d() {
    const int n   = (blockIdx.z * gridDim.y + blockIdx.y) * gridDim.x + blockIdx.x;
    const int tot = gridDim.x * gridDim.y * gridDim.z;
    return (n & 7) * (tot >> 3) + (n >> 3);
}

// =========================== prep kernels ===========================
__global__ __launch_bounds__(256)
void tpose_cvt_k(const float* __restrict__ in, ushort* __restrict__ out,
                 int K, int N, size_t inStride, size_t outStride) {
    __shared__ float T[32][33];
    const float* ib = in  + (size_t)blockIdx.z * inStride;
    ushort*      ob = out + (size_t)blockIdx.z * outStride;
    const int k0 = blockIdx.x * 32, n0 = blockIdx.y * 32;
    const int tx = threadIdx.x & 31, ty = threadIdx.x >> 5;
#pragma unroll
    for (int i = 0; i < 4; ++i) T[ty + 8 * i][tx] = ib[(size_t)(k0 + ty + 8 * i) * N + n0 + tx];
    __syncthreads();
#pragma unroll
    for (int i = 0; i < 4; ++i)
        ob[(size_t)(n0 + ty + 8 * i) * K + k0 + tx] = f2b(T[tx][ty + 8 * i]);
}

// Wp fold: diff segment absorbed -> WpT'[n][k'] over K'=6144
__global__ __launch_bounds__(256)
void tpose_wp_k(const float* __restrict__ Wp, ushort* __restrict__ out) {
    __shared__ float T[32][33];
    const int k0 = blockIdx.x * 32, n0 = blockIdx.y * 32;
    const int tx = threadIdx.x & 31, ty = threadIdx.x >> 5;
#pragma unroll
    for (int i = 0; i < 4; ++i) {
        const int k = k0 + ty + 8 * i, n = n0 + tx;
        float v = Wp[(size_t)k * HH + n];
        if (k < DD)           v += Wp[(size_t)(k + 6 * DD) * HH + n];
        else if (k < 2 * DD)  v -= Wp[(size_t)(k + 5 * DD) * HH + n];
        T[ty + 8 * i][tx] = v;
    }
    __syncthreads();
#pragma unroll
    for (int i = 0; i < 4; ++i)
        out[(size_t)(n0 + ty + 8 * i) * KOUT6 + k0 + tx] = f2b(T[tx][ty + 8 * i]);
}

// merged: XbE row-major copy + per-batch transpose (PbT/HbT), one read of P/H
__global__ __launch_bounds__(256)
void prep_xt_k(const float* __restrict__ P, const float* __restrict__ H,
               ushort* __restrict__ XbE, ushort* __restrict__ PbT,
               ushort* __restrict__ HbT) {
    __shared__ float T[32][33];
    const int z = blockIdx.z;                 // 0..63: side*32 + b
    const int side = z >> 5, b = z & 31;
    const float* in = (side ? H : P) + (size_t)b * SS * DD;
    ushort* xe = XbE + ((size_t)side * NROW + (size_t)b * SS) * DD;
    ushort* xt = (side ? HbT : PbT) + (size_t)b * DD * SS;
    const int d0 = blockIdx.x * 32, s0 = blockIdx.y * 32;
    const int tx = threadIdx.x & 31, ty = threadIdx.x >> 5;
#pragma unroll
    for (int i = 0; i < 4; ++i) {
        const int s = s0 + ty + 8 * i;
        const float v = in[(size_t)s * DD + d0 + tx];
        T[ty + 8 * i][tx] = v;
        xe[(size_t)s * DD + d0 + tx] = f2b(v);
    }
    __syncthreads();
#pragma unroll
    for (int i = 0; i < 4; ++i)
        xt[(size_t)(d0 + ty + 8 * i) * SS + s0 + tx] = f2b(T[tx][ty + 8 * i]);
}

// post-lin prep: Xb = bf16(x), prodb = bf16(x*att)   (alias dead catb region)
__global__ __launch_bounds__(256)
void prep_xprod_k(const float* __restrict__ P, const float* __restrict__ H,
                  const ushort* __restrict__ attAb,
                  ushort* __restrict__ Xb, ushort* __restrict__ prodb) {
    const int idx = blockIdx.x * 256 + threadIdx.x;
    const int row = idx >> 7, chunk = idx & 127;
    const size_t off = (size_t)row * DD + chunk * 8;
    const float* X = (row < NROW) ? (P + off) : (H + off - (size_t)NROW * DD);
    const float4 x0 = ld4(X), x1 = ld4(X + 4);
    float xv[8] = {x0.x, x0.y, x0.z, x0.w, x1.x, x1.y, x1.z, x1.w};
    float av[8];
    b2f8(*(const bf16x8*)&attAb[off], av);
    float pv[8];
#pragma unroll
    for (int j = 0; j < 8; ++j) pv[j] = xv[j] * av[j];
    *(bf16x8*)&Xb[off]    = cvt8(xv);
    *(bf16x8*)&prodb[off] = cvt8(pv);
}

// final reduce (split path): out = relu(out + p1 + bias)
__global__ __launch_bounds__(256)
void reduce_out_k(float* __restrict__ out, const float* __restrict__ p1,
                  const float* __restrict__ bp) {
    const int gid = blockIdx.x * 256 + threadIdx.x;
    const size_t o = (size_t)gid * 4;
    const float4 a = ld4(&out[o]);
    const float4 b = ld4(&p1[o]);
    const float4 bv = ld4(&bp[(int)(o & 511)]);
    *(float4*)&out[o] = make_float4(fmaxf(a.x + b.x + bv.x, 0.f),
                                    fmaxf(a.y + b.y + bv.y, 0.f),
                                    fmaxf(a.z + b.z + bv.z, 0.f),
                                    fmaxf(a.w + b.w + bv.w, 0.f));
}

// =========================== softmax (bf16 in-place, wave-per-row) ===========================
__global__ __launch_bounds__(256)
void softmax4_k(ushort* __restrict__ simPH, ushort* __restrict__ simPHT,
                ushort* __restrict__ simPP, ushort* __restrict__ simHH,
                const int* __restrict__ pma, const int* __restrict__ hma) {
    const int job = blockIdx.y;
    ushort* buf = job == 0 ? simPH : job == 1 ? simPHT : job == 2 ? simPP : simHH;
    const int* mask = job == 0 ? hma : job == 1 ? pma : nullptr;
    const int w = threadIdx.x >> 6, lane = threadIdx.x & 63;
    const int row = blockIdx.x * 4 + w;
    const int b = row >> 8;
    ushort* rp = buf + (size_t)row * SS + lane * 4;
    ushort4 u = *(const ushort4*)rp;
    float z[4], mj[4];
    const ushort uv[4] = {u.x, u.y, u.z, u.w};
#pragma unroll
    for (int c = 0; c < 4; ++c) {
        const float v = b2f(uv[c]);
        float m = 1.f;
        if (mask) m = (float)mask[b * SS + lane * 4 + c];
        mj[c] = m; z[c] = v * m;
    }
    float M = fmaxf(fmaxf(z[0], z[1]), fmaxf(z[2], z[3]));
#pragma unroll
    for (int off = 1; off < 64; off <<= 1) M = fmaxf(M, __shfl_xor(M, off));
    float e[4], r[4], sz = 0.f, sr = 0.f;
#pragma unroll
    for (int c = 0; c < 4; ++c) {
        e[c] = expf(z[c] - M);
        r[c] = e[c] * mj[c];
        sz += e[c]; sr += r[c];
    }
#pragma unroll
    for (int off = 1; off < 64; off <<= 1) {
        sz += __shfl_xor(sz, off);
        sr += __shfl_xor(sr, off);
    }
    ushort4 o;
    if (mask) {
        const float d = 1.f / (sr + EPSF * sz);
        o.x = f2b(r[0] * d); o.y = f2b(r[1] * d); o.z = f2b(r[2] * d); o.w = f2b(r[3] * d);
    } else {
        const float d = 1.f / sz;
        o.x = f2b(e[0] * d); o.y = f2b(e[1] * d); o.z = f2b(e[2] * d); o.w = f2b(e[3] * d);
    }
    *(ushort4*)rp = o;
}

// =========================== colsum: two-stage ===========================
__global__ __launch_bounds__(256)
void colsum_p1_k(const ushort* __restrict__ simPP, const ushort* __restrict__ simHH,
                 const ushort* __restrict__ simPHT, const ushort* __restrict__ simPH,
                 float* __restrict__ pbuf) {
    const int job = blockIdx.y, b = blockIdx.x, rc = blockIdx.z, j = threadIdx.x;
    const ushort* src = job == 0 ? simPP : job == 1 ? simHH : job == 2 ? simPHT : simPH;
    const ushort* Mb = src + (size_t)b * SS * SS + (size_t)rc * 32 * SS;
    float s = 0.f;
#pragma unroll 4
    for (int i = 0; i < 32; ++i) s += b2f(Mb[i * SS + j]);
    pbuf[(((size_t)job * BB + b) * 8 + rc) * SS + j] = s;
}

__global__ __launch_bounds__(256)
void colsum_p2_k(const float* __restrict__ pbuf,
                 float* __restrict__ impS, float* __restrict__ impI) {
    const int job = blockIdx.y, b = blockIdx.x, j = threadIdx.x;
    const float* pb = pbuf + ((size_t)job * BB + b) * 8 * SS;
    float s = 0.f;
#pragma unroll
    for (int rc = 0; rc < 8; ++rc) s += pb[rc * SS + j];
    float* dst = job == 0 ? impS : job == 1 ? impS + NROW : job == 2 ? impI : impI + NROW;
    dst[b * SS + j] = s;
}

// =========================== MFMA common ===========================
// regT [4][128][8]: reg-staged path, row XOR LSWZ (2-way free).
// gllT32 [128][32]: GLL BK=32, sigma swizzle slot = chunk ^ ((row>>1)&3).
// gllT64 [128][64]: GLL BK=64, slot = chunk ^ (row&7).
#define LSWZ(kg, r) ((r) ^ ((kg) << 1))
#define SIG(r) (((r) >> 1) & 3)
#define FRAG_R(T, r) (*(const bf16x8*)T[kq][LSWZ(kq, r)])
#define FRAG_G(T, r) (*(const bf16x8*)&T[r][(kq ^ SIG(r)) * 8])
#define FRAG_G64(T, r, kh) (*(const bf16x8*)&T[r][((((kh) << 2) + kq) ^ ((r) & 7)) * 8])

#define MFMA_TAIL(afr, bfr, ac)                                                      \
    _Pragma("unroll") for (int m = 0; m < 4; ++m)                                    \
        _Pragma("unroll") for (int n = 0; n < 4; ++n)                                \
            ac[m][n] = __builtin_amdgcn_mfma_f32_16x16x32_bf16(                      \
                afr[m], bfr[n], ac[m][n], 0, 0, 0);

#define MFMA_CORE_G64()                                                              \
    _Pragma("unroll") for (int kh_ = 0; kh_ < 2; ++kh_) {                            \
        bf16x8 afr[4], bfr[4];                                                       \
        _Pragma("unroll") for (int m = 0; m < 4; ++m)                                \
            afr[m] = FRAG_G64(As, wr + m * 16 + fr, kh_);                            \
        _Pragma("unroll") for (int n = 0; n < 4; ++n)                                \
            bfr[n] = FRAG_G64(Bs, wc + n * 16 + fr, kh_);                            \
        MFMA_TAIL(afr, bfr, acc)                                                     \
    }

// double-buffer core on [128][32] slices
#define MFMA_CORE_DB(AT, BT_)                                                        \
    {                                                                                \
        bf16x8 afr[4], bfr[4];                                                       \
        _Pragma("unroll") for (int m = 0; m < 4; ++m) afr[m] = FRAG_G(AT, wr + m * 16 + fr); \
        _Pragma("unroll") for (int n = 0; n < 4; ++n) bfr[n] = FRAG_G(BT_, wc + n * 16 + fr); \
        MFMA_TAIL(afr, bfr, acc)                                                     \
    }

#define MFMA_PREAMBLE()                                                              \
    const int tid = threadIdx.x;                                                     \
    const int lane = tid & 63;                                                       \
    const int w = tid >> 6;                                                          \
    const int wr = (w >> 1) * 64, wc = (w & 1) * 64;                                 \
    const int fr = lane & 15;                                                        \
    const int kq = lane >> 4;                                                        \
    const int rq = kq * 4;                                                           \
    f32x4 acc[4][4] = {};

// BK=32 gll stage
#define GLL_STAGE2(seg, pitch, r0, kloc, T)                                          \
    {                                                                                \
        const int rl0_ = w * 32 + (lane >> 2);                                       \
        const int cp_ = lane & 3;                                                    \
        gll16((seg) + (size_t)((r0) + rl0_) * (pitch) + (kloc) + ((cp_ ^ SIG(rl0_)) * 8), \
              &T[w * 32][0]);                                                        \
        const int rl1_ = rl0_ + 16;                                                  \
        gll16((seg) + (size_t)((r0) + rl1_) * (pitch) + (kloc) + ((cp_ ^ SIG(rl1_)) * 8), \
              &T[w * 32 + 16][0]);                                                   \
    }

// BK=64 gll stage: [128][64] tile; 4 instrs/wave, 8 rows each
#define GLL_STAGE64(seg, pitch, r0, kloc, T)                                         \
    {                                                                                \
        _Pragma("unroll")                                                            \
        for (int ii_ = 0; ii_ < 4; ++ii_) {                                          \
            const int rl_ = w * 32 + ii_ * 8 + (lane >> 3);                          \
            const int cp_ = lane & 7;                                                \
            gll16((seg) + (size_t)((r0) + rl_) * (pitch) + (kloc) + (((cp_ ^ (rl_ & 7))) * 8), \
                  &T[w * 32 + ii_ * 8][0]);                                          \
        }                                                                            \
    }

// ---- sim GEMMs (NT, all-gll from bf16 XbE): g0 P@H^T(+T), g1 P@P^T, g2 H@H^T ----
__global__ __launch_bounds__(256)
void mfma_nt_k(const ushort* __restrict__ XbE,
               ushort* __restrict__ simPH, ushort* __restrict__ simPHT,
               ushort* __restrict__ simPP, ushort* __restrict__ simHH) {
    __shared__ __align__(16) ushort As[128][64];
    __shared__ __align__(16) ushort Bs[128][64];
    int orig = swz_orig_3d();                 // grid (2,2,96)
    const int cb = orig & 1; orig >>= 1;
    const int rb = orig & 1; orig >>= 1;
    const int g = orig >> 5, b = orig & 31;
    const ushort* Au = XbE + ((size_t)((g == 2) ? NROW : 0) + (size_t)b * SS) * DD;
    const ushort* Bu = XbE + ((size_t)((g == 1) ? 0 : NROW) + (size_t)b * SS) * DD;
    const int col0 = cb * 128, row0 = rb * 128;
    MFMA_PREAMBLE();
    for (int k0 = 0; k0 < DD; k0 += 64) {
        __syncthreads();
        GLL_STAGE64(Au, DD, row0, k0, As);
        GLL_STAGE64(Bu, DD, col0, k0, Bs);
        __syncthreads();
        MFMA_CORE_G64();
    }
    ushort* Cb = (g == 0 ? simPH : g == 1 ? simPP : simHH) + (size_t)b * SS * SS;
#pragma unroll
    for (int m = 0; m < 4; ++m)
#pragma unroll
        for (int n = 0; n < 4; ++n) {
            const int c = col0 + wc + n * 16 + fr;
            const int r0 = row0 + wr + m * 16 + rq;
#pragma unroll
            for (int r = 0; r < 4; ++r) Cb[(size_t)(r0 + r) * SS + c] = f2b(acc[m][n][r] * SCALE);
            if (g == 0) {
                ushort* Tb = simPHT + (size_t)b * SS * SS;
                ushort4 t;
                t.x = f2b(acc[m][n][0] * SCALE); t.y = f2b(acc[m][n][1] * SCALE);
                t.z = f2b(acc[m][n][2] * SCALE); t.w = f2b(acc[m][n][3] * SCALE);
                *(ushort4*)&Tb[(size_t)c * SS + r0] = t;
            }
        }
}

// ---- att GEMMs (all-gll, BK=64): g0 att_p (mask pm), g1 att_h (mask hm), g2/g3 self ----
__global__ __launch_bounds__(256)
void mfma_att_k(const ushort* __restrict__ ph, const ushort* __restrict__ hp,
                const ushort* __restrict__ spA, const ushort* __restrict__ shA,
                const ushort* __restrict__ PbT, const ushort* __restrict__ HbT,
                const int* __restrict__ pma, const int* __restrict__ hma,
                ushort* __restrict__ attAb, ushort* __restrict__ selfAb) {
    __shared__ __align__(16) ushort As[128][64];
    __shared__ __align__(16) ushort Bs[128][64];
    int orig = swz_orig_3d();                 // grid (8,2,128)
    const int x = orig & 7; orig >>= 3;
    const int y = orig & 1; orig >>= 1;
    const int g = orig >> 5, b = orig & 31;
    const ushort* W  = (g == 0 ? ph : g == 1 ? hp : g == 2 ? spA : shA) + (size_t)b * SS * SS;
    const ushort* BT = ((g == 0 || g == 3) ? HbT : PbT) + (size_t)b * DD * SS;
    const int* rmask = g == 0 ? pma + b * SS : g == 1 ? hma + b * SS : nullptr;
    const int side = (g == 1 || g == 3);
    ushort* Ob = (g < 2 ? attAb : selfAb) + ((size_t)side * NROW + (size_t)b * SS) * DD;
    const int col0 = x * 128, row0 = y * 128;
    MFMA_PREAMBLE();
    for (int k0 = 0; k0 < SS; k0 += 64) {
        __syncthreads();
        GLL_STAGE64(W,  SS, row0, k0, As);
        GLL_STAGE64(BT, SS, col0, k0, Bs);
        __syncthreads();
        MFMA_CORE_G64();
    }
#pragma unroll
    for (int m = 0; m < 4; ++m)
#pragma unroll
        for (int n = 0; n < 4; ++n) {
            const int c = col0 + wc + n * 16 + fr;
#pragma unroll
            for (int r = 0; r < 4; ++r) {
                const int rr = row0 + wr + m * 16 + rq + r;
                const float mm = rmask ? (float)rmask[rr] : 1.0f;
                Ob[(size_t)rr * DD + c] = f2b(acc[m][n][r] * mm);
            }
        }
}

// ---- fuse_pure (dbuf issue-early, 1 sync/tile): kf in {0,1,2,4,5,6} ----
__global__ __launch_bounds__(256)
void mfma_fuse_pure_k(const ushort* __restrict__ Xb, const float* __restrict__ impS,
                      const float* __restrict__ impI, const ushort* __restrict__ W8T,
                      const float* __restrict__ B8v, ushort* __restrict__ catb) {
    __shared__ __align__(16) ushort As[2][128][32];
    __shared__ __align__(16) ushort Bs[2][128][32];
    const int orig = swz_orig_2d();           // grid (12,128)
    const int cb = orig % 12, rb = orig / 12;
    const int kidx = cb >> 1;
    const int kf = kidx + (kidx >= 3 ? 1 : 0);         // 0,1,2,4,5,6
    const int e0 = (cb & 1) * 128, row0 = rb * 128;
    MFMA_PREAMBLE();
    const ushort* Wk = W8T + (size_t)kf * EE * DD;
    GLL_STAGE2(Xb, DD, row0, 0, As[0]);
    GLL_STAGE2(Wk, DD, e0, 0, Bs[0]);
    __syncthreads();
    int cur = 0;
    for (int t = 0; t < DD / 32; ++t) {
        if (t + 1 < DD / 32) {
            GLL_STAGE2(Xb, DD, row0, (t + 1) * 32, As[cur ^ 1]);
            GLL_STAGE2(Wk, DD, e0, (t + 1) * 32, Bs[cur ^ 1]);
        }
        MFMA_CORE_DB(As[cur], Bs[cur]);
        __syncthreads();
        cur ^= 1;
    }
#pragma unroll
    for (int m = 0; m < 4; ++m)
#pragma unroll
        for (int n = 0; n < 4; ++n) {
            const int el = e0 + wc + n * 16 + fr;
            const float bv = B8v[kf * EE + el];
#pragma unroll
            for (int r = 0; r < 4; ++r) {
                const int row = row0 + wr + m * 16 + rq + r;
                const float s_ = impS[row], i_ = impI[row];
                float coef;
                switch (kf) {
                    case 0: coef = s_ * i_;             break;
                    case 1: coef = s_ + i_;             break;
                    case 2: coef = fmaxf(s_, i_);       break;
                    case 4: coef = s_ * i_ + 1.f;       break;
                    case 5: coef = s_ + i_ + 1.f;       break;
                    default: coef = fmaxf(s_, i_) + 1.f; break;
                }
                catb[(size_t)row * FDIM + kf * EE + el] = f2b(coef * acc[m][n][r] + bv);
            }
        }
}

// ---- fuse_dual: kf in {3,7}; cat = (smax-smin)*(pos@W) + g(smin)*(X@W) + B8 ----
__global__ __launch_bounds__(256)
void mfma_fuse_dual_k(const ushort* __restrict__ Xb, const float* __restrict__ impS,
                      const float* __restrict__ impI, const ushort* __restrict__ W8T,
                      const float* __restrict__ B8v, ushort* __restrict__ catb) {
    __shared__ __align__(16) ushort AsX[4][128][8];
    __shared__ __align__(16) ushort AsP[4][128][8];
    __shared__ __align__(16) ushort Bs[128][32];
    const int orig = swz_orig_2d();           // grid (4,128)
    const int cb = orig & 3, rb = orig >> 2;
    const int kf = (cb >> 1) ? 7 : 3;
    const int e0 = (cb & 1) * 128, row0 = rb * 128;
    MFMA_PREAMBLE();
    f32x4 accP[4][4] = {};
    const ushort* Wk = W8T + (size_t)kf * EE * DD;
    for (int k0 = 0; k0 < DD; k0 += 32) {
        bf16x8 xr[2], pr[2];
#pragma unroll
        for (int i = 0; i < 2; ++i) {
            const int cid = tid + i * 256, srow = cid >> 2, skc = (cid & 3) * 8;
            xr[i] = *(const bf16x8*)&Xb[(size_t)(row0 + srow) * DD + k0 + skc];
#pragma unroll
            for (int j = 0; j < 8; ++j) {
                const short s = xr[i][j];
                pr[i][j] = (s & (short)0x8000) ? (short)0 : s;
            }
        }
        __syncthreads();
        GLL_STAGE2(Wk, DD, e0, k0, Bs);
#pragma unroll
        for (int i = 0; i < 2; ++i) {
            const int cid = tid + i * 256, kg = cid & 3, rr = LSWZ(kg, cid >> 2);
            *(bf16x8*)AsX[kg][rr] = xr[i];
            *(bf16x8*)AsP[kg][rr] = pr[i];
        }
        __syncthreads();
        {
            bf16x8 ax[4], ap[4], bfr[4];
#pragma unroll
            for (int m = 0; m < 4; ++m) {
                ax[m] = FRAG_R(AsX, wr + m * 16 + fr);
                ap[m] = FRAG_R(AsP, wr + m * 16 + fr);
            }
#pragma unroll
            for (int n = 0; n < 4; ++n) bfr[n] = FRAG_G(Bs, wc + n * 16 + fr);
            MFMA_TAIL(ax, bfr, acc)
            MFMA_TAIL(ap, bfr, accP)
        }
    }
#pragma unroll
    for (int m = 0; m < 4; ++m)
#pragma unroll
        for (int n = 0; n < 4; ++n) {
            const int el = e0 + wc + n * 16 + fr;
            const float bv = B8v[kf * EE + el];
#pragma unroll
            for (int r = 0; r < 4; ++r) {
                const int row = row0 + wr + m * 16 + rq + r;
                const float s_ = impS[row], i_ = impI[row];
                const float smax = fmaxf(s_, i_), smin = fminf(s_, i_);
                const float gg = (kf == 3) ? smin : smin + 1.f;
                catb[(size_t)row * FDIM + kf * EE + el] =
                    f2b((smax - smin) * accP[m][n][r] + gg * acc[m][n][r] + bv);
            }
        }
}

// ---- lin (dbuf issue-early, 1 sync/tile): pall = relu(cat @ Wl + bl) ----
__global__ __launch_bounds__(256)
void mfma_lin_k(const ushort* __restrict__ A, const ushort* __restrict__ BT,
                const float* __restrict__ bias, ushort* __restrict__ C) {
    __shared__ __align__(16) ushort As[2][128][32];
    __shared__ __align__(16) ushort Bs[2][128][32];
    const int orig = swz_orig_2d();           // grid (16,128)
    const int col0 = (orig & 15) * 128, row0 = (orig >> 4) * 128;
    MFMA_PREAMBLE();
    GLL_STAGE2(A,  FDIM, row0, 0, As[0]);
    GLL_STAGE2(BT, FDIM, col0, 0, Bs[0]);
    __syncthreads();
    int cur = 0;
    for (int t = 0; t < FDIM / 32; ++t) {
        if (t + 1 < FDIM / 32) {
            GLL_STAGE2(A,  FDIM, row0, (t + 1) * 32, As[cur ^ 1]);
            GLL_STAGE2(BT, FDIM, col0, (t + 1) * 32, Bs[cur ^ 1]);
        }
        MFMA_CORE_DB(As[cur], Bs[cur]);
        __syncthreads();
        cur ^= 1;
    }
#pragma unroll
    for (int m = 0; m < 4; ++m)
#pragma unroll
        for (int n = 0; n < 4; ++n) {
            const int c = col0 + wc + n * 16 + fr;
            const float bv = bias[c];
#pragma unroll
            for (int r = 0; r < 4; ++r) {
                const int rr = row0 + wr + m * 16 + rq + r;
                C[(size_t)rr * FDIM + c] = f2b(fmaxf(acc[m][n][r] + bv, 0.f));
            }
        }
}

// ---- out (dbuf issue-early): enh'(K'=6144) @ Wp'; K-split on z ----
__device__ inline void out_seg(int k0, const ushort* Xb, const ushort* attAb,
                               const ushort* selfAb, const ushort* pallb,
                               const ushort* prodb,
                               const ushort*& seg, int& pitch, int& kloc) {
    switch (k0 >> 10) {
        case 0:  seg = Xb;     pitch = DD;   kloc = k0;          break;
        case 1:  seg = attAb;  pitch = DD;   kloc = k0 - DD;     break;
        case 2:  seg = selfAb; pitch = DD;   kloc = k0 - 2 * DD; break;
        case 3:
        case 4:  seg = pallb;  pitch = FDIM; kloc = k0 - 3 * DD; break;
        default: seg = prodb;  pitch = DD;   kloc = k0 - 5 * DD; break;
    }
}

__global__ __launch_bounds__(256)
void mfma_out_k(const ushort* __restrict__ Xb, const ushort* __restrict__ attAb,
                const ushort* __restrict__ selfAb, const ushort* __restrict__ pallb,
                const ushort* __restrict__ prodb, const ushort* __restrict__ WpT,
                const float* __restrict__ bp, float* __restrict__ dst0,
                float* __restrict__ dst1, int kchunk, int finalize) {
    __shared__ __align__(16) ushort As[2][128][32];
    __shared__ __align__(16) ushort Bs[2][128][32];
    int orig = swz_orig_3d();                 // grid (4,128,z)
    const int x = orig & 3; orig >>= 2;
    const int y = orig & 127; orig >>= 7;
    const int z = orig;
    const int col0 = x * 128, row0 = y * 128;
    const int kbase = z * kchunk;
    float* dst = z == 0 ? dst0 : dst1;
    MFMA_PREAMBLE();
    {
        const ushort* seg; int pitch, kloc;
        out_seg(kbase, Xb, attAb, selfAb, pallb, prodb, seg, pitch, kloc);
        GLL_STAGE2(seg, pitch, row0, kloc, As[0]);
        GLL_STAGE2(WpT, KOUT6, col0, kbase, Bs[0]);
    }
    __syncthreads();
    int cur = 0;
    const int NT = kchunk / 32;
    for (int t = 0; t < NT; ++t) {
        if (t + 1 < NT) {
            const int k0 = kbase + (t + 1) * 32;
            const ushort* seg; int pitch, kloc;
            out_seg(k0, Xb, attAb, selfAb, pallb, prodb, seg, pitch, kloc);
            GLL_STAGE2(seg, pitch, row0, kloc, As[cur ^ 1]);
            GLL_STAGE2(WpT, KOUT6, col0, k0, Bs[cur ^ 1]);
        }
        MFMA_CORE_DB(As[cur], Bs[cur]);
        __syncthreads();
        cur ^= 1;
    }
#pragma unroll
    for (int m = 0; m < 4; ++m)
#pragma unroll
        for (int n = 0; n < 4; ++n) {
            const int c = col0 + wc + n * 16 + fr;
            const float bv = finalize ? bp[c] : 0.f;
#pragma unroll
            for (int r = 0; r < 4; ++r) {
                const int rr = row0 + wr + m * 16 + rq + r;
                const float v = acc[m][n][r] + bv;
                dst[(size_t)rr * HH + c] = finalize ? fmaxf(v, 0.f) : v;
            }
        }
}

// =========================== launcher ===========================
// Workspace (unchanged, proven-safe):
//   region0 67.1: [sims 16.8 | PbT/HbT 33.5] -> catb -> [Xb | prodb]
//   att/self 67.1 | pallb 67.1 (XbE squats [0:33.5] pre-lin)
//   weights 18.9 | imp 0.13 | pbuf 1.05 | part1 33.6 (split only if ws allows)
extern "C" void kernel_launch(void* const* d_in, const int* in_sizes, int n_in,
                              void* d_out, int out_size, void* d_ws, size_t ws_size,
                              hipStream_t stream) {
    const float* P   = (const float*)d_in[0];
    const float* Hb  = (const float*)d_in[1];
    const int*   pma = (const int*)d_in[2];
    const int*   hma = (const int*)d_in[3];
    const float* W8  = (const float*)d_in[4];
    const float* B8v = (const float*)d_in[5];
    const float* Wl  = (const float*)d_in[6];
    const float* bl  = (const float*)d_in[7];
    const float* Wp  = (const float*)d_in[8];
    const float* bp  = (const float*)d_in[9];

    char* base = (char*)d_ws;
    ushort* simPH  = (ushort*)base;
    ushort* simPHT = simPH  + SIMSZ;
    ushort* simPP  = simPHT + SIMSZ;
    ushort* simHH  = simPP  + SIMSZ;
    ushort* PbT    = simHH + SIMSZ;
    ushort* HbT    = PbT + (size_t)NROW * DD;
    ushort* catb   = (ushort*)base;                    // alias of region0
    ushort* Xb     = (ushort*)base;                    // alias (post-lin)
    ushort* prodb  = Xb + (size_t)NROW2 * DD;          // alias (post-lin)
    char* cur = base + (size_t)NROW2 * FDIM * 2;       // fixed 67.1 MB region0
    auto alloc_f = [&](size_t n) { float*  p = (float*)cur;  cur += n * 4; return p; };
    auto alloc_u = [&](size_t n) { ushort* p = (ushort*)cur; cur += n * 2; return p; };
    float*  impS   = alloc_f(NROW2);
    float*  impI   = alloc_f(NROW2);
    ushort* attAb  = alloc_u((size_t)NROW2 * DD);
    ushort* selfAb = alloc_u((size_t)NROW2 * DD);
    ushort* pallb  = alloc_u((size_t)NROW2 * FDIM);
    ushort* WlT    = alloc_u((size_t)FDIM * FDIM);
    ushort* WpT    = alloc_u((size_t)HH * KOUT6);
    ushort* W8T    = alloc_u((size_t)8 * EE * DD);
    float*  pbuf   = alloc_f((size_t)4 * BB * 8 * SS); // colsum partials (1 MB)
    float*  part1  = alloc_f((size_t)NROW2 * HH);      // only used if split

    ushort* XbE = pallb;                               // Xb_early squats in pallb

    const size_t need_split = (size_t)((char*)(part1 + (size_t)NROW2 * HH) - base);
    const bool split = ws_size >= need_split;

    float* outp = (float*)d_out;
    const dim3 blk(256);

    // ---- preps (merged X copy + transpose: one read of P/H)
    prep_xt_k<<<dim3(DD / 32, SS / 32, 2 * BB), blk, 0, stream>>>(P, Hb, XbE, PbT, HbT);
    tpose_cvt_k<<<dim3(FDIM / 32, FDIM / 32, 1), blk, 0, stream>>>(Wl, WlT, FDIM, FDIM, 0, 0);
    tpose_wp_k<<<dim3(KOUT6 / 32, HH / 32, 1), blk, 0, stream>>>(Wp, WpT);
    tpose_cvt_k<<<dim3(DD / 32, EE / 32, 8), blk, 0, stream>>>(W8, W8T, DD, EE,
                                                               (size_t)DD * EE, (size_t)EE * DD);

    // ---- attention pipeline
    mfma_nt_k<<<dim3(2, 2, 96), blk, 0, stream>>>(XbE, simPH, simPHT, simPP, simHH);
    softmax4_k<<<dim3(NROW / 4, 4), blk, 0, stream>>>(simPH, simPHT, simPP, simHH, pma, hma);
    colsum_p1_k<<<dim3(BB, 4, 8), blk, 0, stream>>>(simPP, simHH, simPHT, simPH, pbuf);
    colsum_p2_k<<<dim3(BB, 4), blk, 0, stream>>>(pbuf, impS, impI);
    mfma_att_k<<<dim3(8, 2, 128), blk, 0, stream>>>(simPH, simPHT, simPP, simHH, PbT, HbT,
                                                    pma, hma, attAb, selfAb);

    // ---- fused projection pipeline
    mfma_fuse_pure_k<<<dim3(12, 128), blk, 0, stream>>>(XbE, impS, impI, W8T, B8v, catb);
    mfma_fuse_dual_k<<<dim3(4, 128), blk, 0, stream>>>(XbE, impS, impI, W8T, B8v, catb);
    mfma_lin_k<<<dim3(16, 128), blk, 0, stream>>>(catb, WlT, bl, pallb);
    prep_xprod_k<<<dim3(NROW2 * DD / 8 / 256), blk, 0, stream>>>(P, Hb, attAb, Xb, prodb);
    if (split) {
        mfma_out_k<<<dim3(4, 128, 2), blk, 0, stream>>>(Xb, attAb, selfAb, pallb, prodb,
                                                        WpT, bp, outp, part1, KOUT6 / 2, 0);
        reduce_out_k<<<dim3(NROW2 * HH / 4 / 256), blk, 0, stream>>>(outp, part1, bp);
    } else {
        mfma_out_k<<<dim3(4, 128, 1), blk, 0, stream>>>(Xb, attAb, selfAb, pallb, prodb,
                                                        WpT, bp, outp, outp, KOUT6, 1);
    }

    (void)in_sizes; (void)n_in; (void)out_size; (void)ws_size;
}

// Round 16
// 657.433 us; speedup vs baseline: 1.0940x; 1.0940x over previous
//
#include <hip/hip_runtime.h>
#include <hip/hip_bf16.h>
#include <cmath>

#define BB 32
#define SS 256
#define DD 1024
#define EE 256
#define FDIM 2048
#define HH 512
#define KOUT6 (6 * 1024)
#define NROW (BB * SS)          // 8192 rows per side
#define NROW2 (2 * NROW)        // 16384 combined
#define SIMSZ ((size_t)BB * SS * SS)

static constexpr float SCALE = 1.0f / 32.0f;   // 1/sqrt(1024)
static constexpr float EPSF  = 1e-13f;

typedef __attribute__((ext_vector_type(8))) short bf16x8;
typedef __attribute__((ext_vector_type(4))) float f32x4;

__device__ inline float4 ld4(const float* p) { return *(const float4*)p; }
__device__ inline ushort f2b(float f) {
    uint x = __float_as_uint(f);
    x += 0x7fffu + ((x >> 16) & 1u);      // round-to-nearest-even
    return (ushort)(x >> 16);
}
__device__ inline float b2f(ushort u) { return __uint_as_float(((uint)u) << 16); }
__device__ inline bf16x8 cvt8(const float* v) {
    bf16x8 r;
#pragma unroll
    for (int j = 0; j < 8; ++j) r[j] = (short)f2b(v[j]);
    return r;
}
__device__ inline void b2f8(bf16x8 v, float* o) {
#pragma unroll
    for (int j = 0; j < 8; ++j) o[j] = b2f((ushort)v[j]);
}

// async global->LDS, 16B/lane; LDS dest = wave-uniform base + lane*16
typedef __attribute__((address_space(1))) const uchar gas_t;
typedef __attribute__((address_space(3))) uchar las_t;
__device__ inline void gll16(const ushort* g, ushort* l) {
    __builtin_amdgcn_global_load_lds((gas_t*)g, (las_t*)l, 16, 0, 0);
}

// XCD-chunked swizzle (grid total must be %8==0)
__device__ inline int swz_orig_2d() {
    const int n   = blockIdx.y * gridDim.x + blockIdx.x;
    const int tot = gridDim.x * gridDim.y;
    return (n & 7) * (tot >> 3) + (n >> 3);
}
__device__ inline int swz_orig_3d() {
    const int n   = (blockIdx.z * gridDim.y + blockIdx.y) * gridDim.x + blockIdx.x;
    const int tot = gridDim.x * gridDim.y * gridDim.z;
    return (n & 7) * (tot >> 3) + (n >> 3);
}

// =========================== prep kernels ===========================
__global__ __launch_bounds__(256)
void tpose_cvt_k(const float* __restrict__ in, ushort* __restrict__ out,
                 int K, int N, size_t inStride, size_t outStride) {
    __shared__ float T[32][33];
    const float* ib = in  + (size_t)blockIdx.z * inStride;
    ushort*      ob = out + (size_t)blockIdx.z * outStride;
    const int k0 = blockIdx.x * 32, n0 = blockIdx.y * 32;
    const int tx = threadIdx.x & 31, ty = threadIdx.x >> 5;
#pragma unroll
    for (int i = 0; i < 4; ++i) T[ty + 8 * i][tx] = ib[(size_t)(k0 + ty + 8 * i) * N + n0 + tx];
    __syncthreads();
#pragma unroll
    for (int i = 0; i < 4; ++i)
        ob[(size_t)(n0 + ty + 8 * i) * K + k0 + tx] = f2b(T[tx][ty + 8 * i]);
}

// Wp fold: diff segment absorbed -> WpT'[n][k'] over K'=6144
__global__ __launch_bounds__(256)
void tpose_wp_k(const float* __restrict__ Wp, ushort* __restrict__ out) {
    __shared__ float T[32][33];
    const int k0 = blockIdx.x * 32, n0 = blockIdx.y * 32;
    const int tx = threadIdx.x & 31, ty = threadIdx.x >> 5;
#pragma unroll
    for (int i = 0; i < 4; ++i) {
        const int k = k0 + ty + 8 * i, n = n0 + tx;
        float v = Wp[(size_t)k * HH + n];
        if (k < DD)           v += Wp[(size_t)(k + 6 * DD) * HH + n];
        else if (k < 2 * DD)  v -= Wp[(size_t)(k + 5 * DD) * HH + n];
        T[ty + 8 * i][tx] = v;
    }
    __syncthreads();
#pragma unroll
    for (int i = 0; i < 4; ++i)
        out[(size_t)(n0 + ty + 8 * i) * KOUT6 + k0 + tx] = f2b(T[tx][ty + 8 * i]);
}

// merged: XbE row-major copy + per-batch transpose (PbT/HbT), one read of P/H
__global__ __launch_bounds__(256)
void prep_xt_k(const float* __restrict__ P, const float* __restrict__ H,
               ushort* __restrict__ XbE, ushort* __restrict__ PbT,
               ushort* __restrict__ HbT) {
    __shared__ float T[32][33];
    const int z = blockIdx.z;                 // 0..63: side*32 + b
    const int side = z >> 5, b = z & 31;
    const float* in = (side ? H : P) + (size_t)b * SS * DD;
    ushort* xe = XbE + ((size_t)side * NROW + (size_t)b * SS) * DD;
    ushort* xt = (side ? HbT : PbT) + (size_t)b * DD * SS;
    const int d0 = blockIdx.x * 32, s0 = blockIdx.y * 32;
    const int tx = threadIdx.x & 31, ty = threadIdx.x >> 5;
#pragma unroll
    for (int i = 0; i < 4; ++i) {
        const int s = s0 + ty + 8 * i;
        const float v = in[(size_t)s * DD + d0 + tx];
        T[ty + 8 * i][tx] = v;
        xe[(size_t)s * DD + d0 + tx] = f2b(v);
    }
    __syncthreads();
#pragma unroll
    for (int i = 0; i < 4; ++i)
        xt[(size_t)(d0 + ty + 8 * i) * SS + s0 + tx] = f2b(T[tx][ty + 8 * i]);
}

// post-lin prep: Xb = bf16(x), prodb = bf16(x*att)   (alias dead catb region)
__global__ __launch_bounds__(256)
void prep_xprod_k(const float* __restrict__ P, const float* __restrict__ H,
                  const ushort* __restrict__ attAb,
                  ushort* __restrict__ Xb, ushort* __restrict__ prodb) {
    const int idx = blockIdx.x * 256 + threadIdx.x;
    const int row = idx >> 7, chunk = idx & 127;
    const size_t off = (size_t)row * DD + chunk * 8;
    const float* X = (row < NROW) ? (P + off) : (H + off - (size_t)NROW * DD);
    const float4 x0 = ld4(X), x1 = ld4(X + 4);
    float xv[8] = {x0.x, x0.y, x0.z, x0.w, x1.x, x1.y, x1.z, x1.w};
    float av[8];
    b2f8(*(const bf16x8*)&attAb[off], av);
    float pv[8];
#pragma unroll
    for (int j = 0; j < 8; ++j) pv[j] = xv[j] * av[j];
    *(bf16x8*)&Xb[off]    = cvt8(xv);
    *(bf16x8*)&prodb[off] = cvt8(pv);
}

// final reduce (split path): out = relu(out + p1 + bias)
__global__ __launch_bounds__(256)
void reduce_out_k(float* __restrict__ out, const float* __restrict__ p1,
                  const float* __restrict__ bp) {
    const int gid = blockIdx.x * 256 + threadIdx.x;
    const size_t o = (size_t)gid * 4;
    const float4 a = ld4(&out[o]);
    const float4 b = ld4(&p1[o]);
    const float4 bv = ld4(&bp[(int)(o & 511)]);
    *(float4*)&out[o] = make_float4(fmaxf(a.x + b.x + bv.x, 0.f),
                                    fmaxf(a.y + b.y + bv.y, 0.f),
                                    fmaxf(a.z + b.z + bv.z, 0.f),
                                    fmaxf(a.w + b.w + bv.w, 0.f));
}

// =========================== softmax (bf16 in-place, wave-per-row) ===========================
__global__ __launch_bounds__(256)
void softmax4_k(ushort* __restrict__ simPH, ushort* __restrict__ simPHT,
                ushort* __restrict__ simPP, ushort* __restrict__ simHH,
                const int* __restrict__ pma, const int* __restrict__ hma) {
    const int job = blockIdx.y;
    ushort* buf = job == 0 ? simPH : job == 1 ? simPHT : job == 2 ? simPP : simHH;
    const int* mask = job == 0 ? hma : job == 1 ? pma : nullptr;
    const int w = threadIdx.x >> 6, lane = threadIdx.x & 63;
    const int row = blockIdx.x * 4 + w;
    const int b = row >> 8;
    ushort* rp = buf + (size_t)row * SS + lane * 4;
    ushort4 u = *(const ushort4*)rp;
    float z[4], mj[4];
    const ushort uv[4] = {u.x, u.y, u.z, u.w};
#pragma unroll
    for (int c = 0; c < 4; ++c) {
        const float v = b2f(uv[c]);
        float m = 1.f;
        if (mask) m = (float)mask[b * SS + lane * 4 + c];
        mj[c] = m; z[c] = v * m;
    }
    float M = fmaxf(fmaxf(z[0], z[1]), fmaxf(z[2], z[3]));
#pragma unroll
    for (int off = 1; off < 64; off <<= 1) M = fmaxf(M, __shfl_xor(M, off));
    float e[4], r[4], sz = 0.f, sr = 0.f;
#pragma unroll
    for (int c = 0; c < 4; ++c) {
        e[c] = expf(z[c] - M);
        r[c] = e[c] * mj[c];
        sz += e[c]; sr += r[c];
    }
#pragma unroll
    for (int off = 1; off < 64; off <<= 1) {
        sz += __shfl_xor(sz, off);
        sr += __shfl_xor(sr, off);
    }
    ushort4 o;
    if (mask) {
        const float d = 1.f / (sr + EPSF * sz);
        o.x = f2b(r[0] * d); o.y = f2b(r[1] * d); o.z = f2b(r[2] * d); o.w = f2b(r[3] * d);
    } else {
        const float d = 1.f / sz;
        o.x = f2b(e[0] * d); o.y = f2b(e[1] * d); o.z = f2b(e[2] * d); o.w = f2b(e[3] * d);
    }
    *(ushort4*)rp = o;
}

// =========================== colsum: two-stage ===========================
__global__ __launch_bounds__(256)
void colsum_p1_k(const ushort* __restrict__ simPP, const ushort* __restrict__ simHH,
                 const ushort* __restrict__ simPHT, const ushort* __restrict__ simPH,
                 float* __restrict__ pbuf) {
    const int job = blockIdx.y, b = blockIdx.x, rc = blockIdx.z, j = threadIdx.x;
    const ushort* src = job == 0 ? simPP : job == 1 ? simHH : job == 2 ? simPHT : simPH;
    const ushort* Mb = src + (size_t)b * SS * SS + (size_t)rc * 32 * SS;
    float s = 0.f;
#pragma unroll 4
    for (int i = 0; i < 32; ++i) s += b2f(Mb[i * SS + j]);
    pbuf[(((size_t)job * BB + b) * 8 + rc) * SS + j] = s;
}

__global__ __launch_bounds__(256)
void colsum_p2_k(const float* __restrict__ pbuf,
                 float* __restrict__ impS, float* __restrict__ impI) {
    const int job = blockIdx.y, b = blockIdx.x, j = threadIdx.x;
    const float* pb = pbuf + ((size_t)job * BB + b) * 8 * SS;
    float s = 0.f;
#pragma unroll
    for (int rc = 0; rc < 8; ++rc) s += pb[rc * SS + j];
    float* dst = job == 0 ? impS : job == 1 ? impS + NROW : job == 2 ? impI : impI + NROW;
    dst[b * SS + j] = s;
}

// =========================== MFMA common ===========================
// regT [4][128][8]: reg-staged path, row XOR LSWZ (2-way free).
// gllT32 [128][32]: GLL BK=32 path (fuse_dual B), sigma swizzle.
// gllT64 [128][64]: GLL BK=64 path: wave w stages rows [32w,32w+32) in 4
//   instrs of 8 rows; 8 lanes cover one row's full 128B line (coalesced);
//   slot = chunk ^ (row&7) -> per-16-lane frag read 2-way (free floor).
#define LSWZ(kg, r) ((r) ^ ((kg) << 1))
#define SIG(r) (((r) >> 1) & 3)
#define FRAG_R(T, r) (*(const bf16x8*)T[kq][LSWZ(kq, r)])
#define FRAG_G(T, r) (*(const bf16x8*)&T[r][(kq ^ SIG(r)) * 8])
#define FRAG_G64(T, r, kh) (*(const bf16x8*)&T[r][((((kh) << 2) + kq) ^ ((r) & 7)) * 8])

#define MFMA_TAIL(afr, bfr, ac)                                                      \
    _Pragma("unroll") for (int m = 0; m < 4; ++m)                                    \
        _Pragma("unroll") for (int n = 0; n < 4; ++n)                                \
            ac[m][n] = __builtin_amdgcn_mfma_f32_16x16x32_bf16(                      \
                afr[m], bfr[n], ac[m][n], 0, 0, 0);

#define MFMA_CORE_G64()                                                              \
    _Pragma("unroll") for (int kh_ = 0; kh_ < 2; ++kh_) {                            \
        bf16x8 afr[4], bfr[4];                                                       \
        _Pragma("unroll") for (int m = 0; m < 4; ++m)                                \
            afr[m] = FRAG_G64(As, wr + m * 16 + fr, kh_);                            \
        _Pragma("unroll") for (int n = 0; n < 4; ++n)                                \
            bfr[n] = FRAG_G64(Bs, wc + n * 16 + fr, kh_);                            \
        MFMA_TAIL(afr, bfr, acc)                                                     \
    }

#define MFMA_PREAMBLE()                                                              \
    const int tid = threadIdx.x;                                                     \
    const int lane = tid & 63;                                                       \
    const int w = tid >> 6;                                                          \
    const int wr = (w >> 1) * 64, wc = (w & 1) * 64;                                 \
    const int fr = lane & 15;                                                        \
    const int kq = lane >> 4;                                                        \
    const int rq = kq * 4;                                                           \
    f32x4 acc[4][4] = {};

// BK=32 gll stage (fuse_dual B only)
#define GLL_STAGE2(seg, pitch, r0, kloc, T)                                          \
    {                                                                                \
        const int rl0_ = w * 32 + (lane >> 2);                                       \
        const int cp_ = lane & 3;                                                    \
        gll16((seg) + (size_t)((r0) + rl0_) * (pitch) + (kloc) + ((cp_ ^ SIG(rl0_)) * 8), \
              &T[w * 32][0]);                                                        \
        const int rl1_ = rl0_ + 16;                                                  \
        gll16((seg) + (size_t)((r0) + rl1_) * (pitch) + (kloc) + ((cp_ ^ SIG(rl1_)) * 8), \
              &T[w * 32 + 16][0]);                                                   \
    }

// BK=64 gll stage: [128][64] tile; 4 instrs/wave, 8 rows each
#define GLL_STAGE64(seg, pitch, r0, kloc, T)                                         \
    {                                                                                \
        _Pragma("unroll")                                                            \
        for (int ii_ = 0; ii_ < 4; ++ii_) {                                          \
            const int rl_ = w * 32 + ii_ * 8 + (lane >> 3);                          \
            const int cp_ = lane & 7;                                                \
            gll16((seg) + (size_t)((r0) + rl_) * (pitch) + (kloc) + (((cp_ ^ (rl_ & 7))) * 8), \
                  &T[w * 32 + ii_ * 8][0]);                                          \
        }                                                                            \
    }

// ---- sim GEMMs (NT, all-gll from bf16 XbE): g0 P@H^T(+T), g1 P@P^T, g2 H@H^T ----
__global__ __launch_bounds__(256)
void mfma_nt_k(const ushort* __restrict__ XbE,
               ushort* __restrict__ simPH, ushort* __restrict__ simPHT,
               ushort* __restrict__ simPP, ushort* __restrict__ simHH) {
    __shared__ __align__(16) ushort As[128][64];
    __shared__ __align__(16) ushort Bs[128][64];
    int orig = swz_orig_3d();                 // grid (2,2,96)
    const int cb = orig & 1; orig >>= 1;
    const int rb = orig & 1; orig >>= 1;
    const int g = orig >> 5, b = orig & 31;
    const ushort* Au = XbE + ((size_t)((g == 2) ? NROW : 0) + (size_t)b * SS) * DD;
    const ushort* Bu = XbE + ((size_t)((g == 1) ? 0 : NROW) + (size_t)b * SS) * DD;
    const int col0 = cb * 128, row0 = rb * 128;
    MFMA_PREAMBLE();
    for (int k0 = 0; k0 < DD; k0 += 64) {
        __syncthreads();
        GLL_STAGE64(Au, DD, row0, k0, As);
        GLL_STAGE64(Bu, DD, col0, k0, Bs);
        __syncthreads();
        MFMA_CORE_G64();
    }
    ushort* Cb = (g == 0 ? simPH : g == 1 ? simPP : simHH) + (size_t)b * SS * SS;
#pragma unroll
    for (int m = 0; m < 4; ++m)
#pragma unroll
        for (int n = 0; n < 4; ++n) {
            const int c = col0 + wc + n * 16 + fr;
            const int r0 = row0 + wr + m * 16 + rq;
#pragma unroll
            for (int r = 0; r < 4; ++r) Cb[(size_t)(r0 + r) * SS + c] = f2b(acc[m][n][r] * SCALE);
            if (g == 0) {
                ushort* Tb = simPHT + (size_t)b * SS * SS;
                ushort4 t;
                t.x = f2b(acc[m][n][0] * SCALE); t.y = f2b(acc[m][n][1] * SCALE);
                t.z = f2b(acc[m][n][2] * SCALE); t.w = f2b(acc[m][n][3] * SCALE);
                *(ushort4*)&Tb[(size_t)c * SS + r0] = t;
            }
        }
}

// ---- att GEMMs (all-gll, BK=64): g0 att_p (mask pm), g1 att_h (mask hm), g2/g3 self ----
__global__ __launch_bounds__(256)
void mfma_att_k(const ushort* __restrict__ ph, const ushort* __restrict__ hp,
                const ushort* __restrict__ spA, const ushort* __restrict__ shA,
                const ushort* __restrict__ PbT, const ushort* __restrict__ HbT,
                const int* __restrict__ pma, const int* __restrict__ hma,
                ushort* __restrict__ attAb, ushort* __restrict__ selfAb) {
    __shared__ __align__(16) ushort As[128][64];
    __shared__ __align__(16) ushort Bs[128][64];
    int orig = swz_orig_3d();                 // grid (8,2,128)
    const int x = orig & 7; orig >>= 3;
    const int y = orig & 1; orig >>= 1;
    const int g = orig >> 5, b = orig & 31;
    const ushort* W  = (g == 0 ? ph : g == 1 ? hp : g == 2 ? spA : shA) + (size_t)b * SS * SS;
    const ushort* BT = ((g == 0 || g == 3) ? HbT : PbT) + (size_t)b * DD * SS;
    const int* rmask = g == 0 ? pma + b * SS : g == 1 ? hma + b * SS : nullptr;
    const int side = (g == 1 || g == 3);
    ushort* Ob = (g < 2 ? attAb : selfAb) + ((size_t)side * NROW + (size_t)b * SS) * DD;
    const int col0 = x * 128, row0 = y * 128;
    MFMA_PREAMBLE();
    for (int k0 = 0; k0 < SS; k0 += 64) {
        __syncthreads();
        GLL_STAGE64(W,  SS, row0, k0, As);
        GLL_STAGE64(BT, SS, col0, k0, Bs);
        __syncthreads();
        MFMA_CORE_G64();
    }
#pragma unroll
    for (int m = 0; m < 4; ++m)
#pragma unroll
        for (int n = 0; n < 4; ++n) {
            const int c = col0 + wc + n * 16 + fr;
#pragma unroll
            for (int r = 0; r < 4; ++r) {
                const int rr = row0 + wr + m * 16 + rq + r;
                const float mm = rmask ? (float)rmask[rr] : 1.0f;
                Ob[(size_t)rr * DD + c] = f2b(acc[m][n][r] * mm);
            }
        }
}

// ---- fuse_pure (BK=64): kf in {0,1,2,4,5,6}; cat = coef[row]*(X@W8_kf) + B8 ----
__global__ __launch_bounds__(256)
void mfma_fuse_pure_k(const ushort* __restrict__ Xb, const float* __restrict__ impS,
                      const float* __restrict__ impI, const ushort* __restrict__ W8T,
                      const float* __restrict__ B8v, ushort* __restrict__ catb) {
    __shared__ __align__(16) ushort As[128][64];
    __shared__ __align__(16) ushort Bs[128][64];
    const int orig = swz_orig_2d();           // grid (12,128)
    const int cb = orig % 12, rb = orig / 12;
    const int kidx = cb >> 1;
    const int kf = kidx + (kidx >= 3 ? 1 : 0);         // 0,1,2,4,5,6
    const int e0 = (cb & 1) * 128, row0 = rb * 128;
    MFMA_PREAMBLE();
    const ushort* Wk = W8T + (size_t)kf * EE * DD;
    for (int k0 = 0; k0 < DD; k0 += 64) {
        __syncthreads();
        GLL_STAGE64(Xb, DD, row0, k0, As);
        GLL_STAGE64(Wk, DD, e0, k0, Bs);
        __syncthreads();
        MFMA_CORE_G64();
    }
#pragma unroll
    for (int m = 0; m < 4; ++m)
#pragma unroll
        for (int n = 0; n < 4; ++n) {
            const int el = e0 + wc + n * 16 + fr;
            const float bv = B8v[kf * EE + el];
#pragma unroll
            for (int r = 0; r < 4; ++r) {
                const int row = row0 + wr + m * 16 + rq + r;
                const float s_ = impS[row], i_ = impI[row];
                float coef;
                switch (kf) {
                    case 0: coef = s_ * i_;             break;
                    case 1: coef = s_ + i_;             break;
                    case 2: coef = fmaxf(s_, i_);       break;
                    case 4: coef = s_ * i_ + 1.f;       break;
                    case 5: coef = s_ + i_ + 1.f;       break;
                    default: coef = fmaxf(s_, i_) + 1.f; break;
                }
                catb[(size_t)row * FDIM + kf * EE + el] = f2b(coef * acc[m][n][r] + bv);
            }
        }
}

// ---- fuse_dual: kf in {3,7}; cat = (smax-smin)*(pos@W) + g(smin)*(X@W) + B8 ----
__global__ __launch_bounds__(256)
void mfma_fuse_dual_k(const ushort* __restrict__ Xb, const float* __restrict__ impS,
                      const float* __restrict__ impI, const ushort* __restrict__ W8T,
                      const float* __restrict__ B8v, ushort* __restrict__ catb) {
    __shared__ __align__(16) ushort AsX[4][128][8];
    __shared__ __align__(16) ushort AsP[4][128][8];
    __shared__ __align__(16) ushort Bs[128][32];
    const int orig = swz_orig_2d();           // grid (4,128)
    const int cb = orig & 3, rb = orig >> 2;
    const int kf = (cb >> 1) ? 7 : 3;
    const int e0 = (cb & 1) * 128, row0 = rb * 128;
    MFMA_PREAMBLE();
    f32x4 accP[4][4] = {};
    const ushort* Wk = W8T + (size_t)kf * EE * DD;
    for (int k0 = 0; k0 < DD; k0 += 32) {
        bf16x8 xr[2], pr[2];
#pragma unroll
        for (int i = 0; i < 2; ++i) {
            const int cid = tid + i * 256, srow = cid >> 2, skc = (cid & 3) * 8;
            xr[i] = *(const bf16x8*)&Xb[(size_t)(row0 + srow) * DD + k0 + skc];
#pragma unroll
            for (int j = 0; j < 8; ++j) {
                const short s = xr[i][j];
                pr[i][j] = (s & (short)0x8000) ? (short)0 : s;
            }
        }
        __syncthreads();
        GLL_STAGE2(Wk, DD, e0, k0, Bs);
#pragma unroll
        for (int i = 0; i < 2; ++i) {
            const int cid = tid + i * 256, kg = cid & 3, rr = LSWZ(kg, cid >> 2);
            *(bf16x8*)AsX[kg][rr] = xr[i];
            *(bf16x8*)AsP[kg][rr] = pr[i];
        }
        __syncthreads();
        {
            bf16x8 ax[4], ap[4], bfr[4];
#pragma unroll
            for (int m = 0; m < 4; ++m) {
                ax[m] = FRAG_R(AsX, wr + m * 16 + fr);
                ap[m] = FRAG_R(AsP, wr + m * 16 + fr);
            }
#pragma unroll
            for (int n = 0; n < 4; ++n) bfr[n] = FRAG_G(Bs, wc + n * 16 + fr);
            MFMA_TAIL(ax, bfr, acc)
            MFMA_TAIL(ap, bfr, accP)
        }
    }
#pragma unroll
    for (int m = 0; m < 4; ++m)
#pragma unroll
        for (int n = 0; n < 4; ++n) {
            const int el = e0 + wc + n * 16 + fr;
            const float bv = B8v[kf * EE + el];
#pragma unroll
            for (int r = 0; r < 4; ++r) {
                const int row = row0 + wr + m * 16 + rq + r;
                const float s_ = impS[row], i_ = impI[row];
                const float smax = fmaxf(s_, i_), smin = fminf(s_, i_);
                const float gg = (kf == 3) ? smin : smin + 1.f;
                catb[(size_t)row * FDIM + kf * EE + el] =
                    f2b((smax - smin) * accP[m][n][r] + gg * acc[m][n][r] + bv);
            }
        }
}

// ---- lin (BK=64): pall = relu(cat @ Wl + bl) ----
__global__ __launch_bounds__(256)
void mfma_lin_k(const ushort* __restrict__ A, const ushort* __restrict__ BT,
                const float* __restrict__ bias, ushort* __restrict__ C) {
    __shared__ __align__(16) ushort As[128][64];
    __shared__ __align__(16) ushort Bs[128][64];
    const int orig = swz_orig_2d();           // grid (16,128)
    const int col0 = (orig & 15) * 128, row0 = (orig >> 4) * 128;
    MFMA_PREAMBLE();
    for (int k0 = 0; k0 < FDIM; k0 += 64) {
        __syncthreads();
        GLL_STAGE64(A,  FDIM, row0, k0, As);
        GLL_STAGE64(BT, FDIM, col0, k0, Bs);
        __syncthreads();
        MFMA_CORE_G64();
    }
#pragma unroll
    for (int m = 0; m < 4; ++m)
#pragma unroll
        for (int n = 0; n < 4; ++n) {
            const int c = col0 + wc + n * 16 + fr;
            const float bv = bias[c];
#pragma unroll
            for (int r = 0; r < 4; ++r) {
                const int rr = row0 + wr + m * 16 + rq + r;
                C[(size_t)rr * FDIM + c] = f2b(fmaxf(acc[m][n][r] + bv, 0.f));
            }
        }
}

// ---- out (BK=64): enh'(K'=6144) @ Wp'; optional K-split across blockIdx.z ----
__device__ inline void out_seg(int k0, const ushort* Xb, const ushort* attAb,
                               const ushort* selfAb, const ushort* pallb,
                               const ushort* prodb,
                               const ushort*& seg, int& pitch, int& kloc) {
    switch (k0 >> 10) {
        case 0:  seg = Xb;     pitch = DD;   kloc = k0;          break;
        case 1:  seg = attAb;  pitch = DD;   kloc = k0 - DD;     break;
        case 2:  seg = selfAb; pitch = DD;   kloc = k0 - 2 * DD; break;
        case 3:
        case 4:  seg = pallb;  pitch = FDIM; kloc = k0 - 3 * DD; break;
        default: seg = prodb;  pitch = DD;   kloc = k0 - 5 * DD; break;
    }
}

__global__ __launch_bounds__(256)
void mfma_out_k(const ushort* __restrict__ Xb, const ushort* __restrict__ attAb,
                const ushort* __restrict__ selfAb, const ushort* __restrict__ pallb,
                const ushort* __restrict__ prodb, const ushort* __restrict__ WpT,
                const float* __restrict__ bp, float* __restrict__ dst0,
                float* __restrict__ dst1, int kchunk, int finalize) {
    __shared__ __align__(16) ushort As[128][64];
    __shared__ __align__(16) ushort Bs[128][64];
    int orig = swz_orig_3d();                 // grid (4,128,z)
    const int x = orig & 3; orig >>= 2;
    const int y = orig & 127; orig >>= 7;
    const int z = orig;
    const int col0 = x * 128, row0 = y * 128;
    const int kbase = z * kchunk;
    float* dst = z == 0 ? dst0 : dst1;
    MFMA_PREAMBLE();
    for (int t = 0; t < kchunk / 64; ++t) {
        const int k0 = kbase + t * 64;
        const ushort* seg; int pitch, kloc;
        out_seg(k0, Xb, attAb, selfAb, pallb, prodb, seg, pitch, kloc);
        __syncthreads();
        GLL_STAGE64(seg, pitch, row0, kloc, As);
        GLL_STAGE64(WpT, KOUT6, col0, k0, Bs);
        __syncthreads();
        MFMA_CORE_G64();
    }
#pragma unroll
    for (int m = 0; m < 4; ++m)
#pragma unroll
        for (int n = 0; n < 4; ++n) {
            const int c = col0 + wc + n * 16 + fr;
            const float bv = finalize ? bp[c] : 0.f;
#pragma unroll
            for (int r = 0; r < 4; ++r) {
                const int rr = row0 + wr + m * 16 + rq + r;
                const float v = acc[m][n][r] + bv;
                dst[(size_t)rr * HH + c] = finalize ? fmaxf(v, 0.f) : v;
            }
        }
}

// =========================== launcher ===========================
// Workspace (unchanged, proven-safe):
//   region0 67.1: [sims 16.8 | PbT/HbT 33.5] -> catb -> [Xb | prodb]
//   att/self 67.1 | pallb 67.1 (XbE squats [0:33.5] pre-lin)
//   weights 18.9 | imp 0.13 | pbuf 1.05 | part1 33.6 (split only if ws allows)
extern "C" void kernel_launch(void* const* d_in, const int* in_sizes, int n_in,
                              void* d_out, int out_size, void* d_ws, size_t ws_size,
                              hipStream_t stream) {
    const float* P   = (const float*)d_in[0];
    const float* Hb  = (const float*)d_in[1];
    const int*   pma = (const int*)d_in[2];
    const int*   hma = (const int*)d_in[3];
    const float* W8  = (const float*)d_in[4];
    const float* B8v = (const float*)d_in[5];
    const float* Wl  = (const float*)d_in[6];
    const float* bl  = (const float*)d_in[7];
    const float* Wp  = (const float*)d_in[8];
    const float* bp  = (const float*)d_in[9];

    char* base = (char*)d_ws;
    ushort* simPH  = (ushort*)base;
    ushort* simPHT = simPH  + SIMSZ;
    ushort* simPP  = simPHT + SIMSZ;
    ushort* simHH  = simPP  + SIMSZ;
    ushort* PbT    = simHH + SIMSZ;
    ushort* HbT    = PbT + (size_t)NROW * DD;
    ushort* catb   = (ushort*)base;                    // alias of region0
    ushort* Xb     = (ushort*)base;                    // alias (post-lin)
    ushort* prodb  = Xb + (size_t)NROW2 * DD;          // alias (post-lin)
    char* cur = base + (size_t)NROW2 * FDIM * 2;       // fixed 67.1 MB region0
    auto alloc_f = [&](size_t n) { float*  p = (float*)cur;  cur += n * 4; return p; };
    auto alloc_u = [&](size_t n) { ushort* p = (ushort*)cur; cur += n * 2; return p; };
    float*  impS   = alloc_f(NROW2);
    float*  impI   = alloc_f(NROW2);
    ushort* attAb  = alloc_u((size_t)NROW2 * DD);
    ushort* selfAb = alloc_u((size_t)NROW2 * DD);
    ushort* pallb  = alloc_u((size_t)NROW2 * FDIM);
    ushort* WlT    = alloc_u((size_t)FDIM * FDIM);
    ushort* WpT    = alloc_u((size_t)HH * KOUT6);
    ushort* W8T    = alloc_u((size_t)8 * EE * DD);
    float*  pbuf   = alloc_f((size_t)4 * BB * 8 * SS); // colsum partials (1 MB)
    float*  part1  = alloc_f((size_t)NROW2 * HH);      // only used if split

    ushort* XbE = pallb;                               // Xb_early squats in pallb

    const size_t need_split = (size_t)((char*)(part1 + (size_t)NROW2 * HH) - base);
    const bool split = ws_size >= need_split;

    float* outp = (float*)d_out;
    const dim3 blk(256);

    // ---- preps (merged X copy + transpose: one read of P/H)
    prep_xt_k<<<dim3(DD / 32, SS / 32, 2 * BB), blk, 0, stream>>>(P, Hb, XbE, PbT, HbT);
    tpose_cvt_k<<<dim3(FDIM / 32, FDIM / 32, 1), blk, 0, stream>>>(Wl, WlT, FDIM, FDIM, 0, 0);
    tpose_wp_k<<<dim3(KOUT6 / 32, HH / 32, 1), blk, 0, stream>>>(Wp, WpT);
    tpose_cvt_k<<<dim3(DD / 32, EE / 32, 8), blk, 0, stream>>>(W8, W8T, DD, EE,
                                                               (size_t)DD * EE, (size_t)EE * DD);

    // ---- attention pipeline
    mfma_nt_k<<<dim3(2, 2, 96), blk, 0, stream>>>(XbE, simPH, simPHT, simPP, simHH);
    softmax4_k<<<dim3(NROW / 4, 4), blk, 0, stream>>>(simPH, simPHT, simPP, simHH, pma, hma);
    colsum_p1_k<<<dim3(BB, 4, 8), blk, 0, stream>>>(simPP, simHH, simPHT, simPH, pbuf);
    colsum_p2_k<<<dim3(BB, 4), blk, 0, stream>>>(pbuf, impS, impI);
    mfma_att_k<<<dim3(8, 2, 128), blk, 0, stream>>>(simPH, simPHT, simPP, simHH, PbT, HbT,
                                                    pma, hma, attAb, selfAb);

    // ---- fused projection pipeline
    mfma_fuse_pure_k<<<dim3(12, 128), blk, 0, stream>>>(XbE, impS, impI, W8T, B8v, catb);
    mfma_fuse_dual_k<<<dim3(4, 128), blk, 0, stream>>>(XbE, impS, impI, W8T, B8v, catb);
    mfma_lin_k<<<dim3(16, 128), blk, 0, stream>>>(catb, WlT, bl, pallb);
    prep_xprod_k<<<dim3(NROW2 * DD / 8 / 256), blk, 0, stream>>>(P, Hb, attAb, Xb, prodb);
    if (split) {
        mfma_out_k<<<dim3(4, 128, 2), blk, 0, stream>>>(Xb, attAb, selfAb, pallb, prodb,
                                                        WpT, bp, outp, part1, KOUT6 / 2, 0);
        reduce_out_k<<<dim3(NROW2 * HH / 4 / 256), blk, 0, stream>>>(outp, part1, bp);
    } else {
        mfma_out_k<<<dim3(4, 128, 1), blk, 0, stream>>>(Xb, attAb, selfAb, pallb, prodb,
                                                        WpT, bp, outp, outp, KOUT6, 1);
    }

    (void)in_sizes; (void)n_in; (void)out_size; (void)ws_size;
}

// Round 17
// 649.700 us; speedup vs baseline: 1.1071x; 1.0119x over previous
//
#include <hip/hip_runtime.h>
#include <hip/hip_bf16.h>
#include <cmath>

#define BB 32
#define SS 256
#define DD 1024
#define EE 256
#define FDIM 2048
#define HH 512
#define KOUT6 (6 * 1024)
#define NROW (BB * SS)          // 8192 rows per side
#define NROW2 (2 * NROW)        // 16384 combined
#define SIMSZ ((size_t)BB * SS * SS)

static constexpr float SCALE = 1.0f / 32.0f;   // 1/sqrt(1024)
static constexpr float EPSF  = 1e-13f;

typedef __attribute__((ext_vector_type(8))) short bf16x8;
typedef __attribute__((ext_vector_type(4))) float f32x4;

__device__ inline float4 ld4(const float* p) { return *(const float4*)p; }
__device__ inline ushort f2b(float f) {
    uint x = __float_as_uint(f);
    x += 0x7fffu + ((x >> 16) & 1u);      // round-to-nearest-even
    return (ushort)(x >> 16);
}
__device__ inline float b2f(ushort u) { return __uint_as_float(((uint)u) << 16); }
__device__ inline bf16x8 cvt8(const float* v) {
    bf16x8 r;
#pragma unroll
    for (int j = 0; j < 8; ++j) r[j] = (short)f2b(v[j]);
    return r;
}
__device__ inline void b2f8(bf16x8 v, float* o) {
#pragma unroll
    for (int j = 0; j < 8; ++j) o[j] = b2f((ushort)v[j]);
}

// async global->LDS, 16B/lane; LDS dest = wave-uniform base + lane*16
typedef __attribute__((address_space(1))) const uchar gas_t;
typedef __attribute__((address_space(3))) uchar las_t;
__device__ inline void gll16(const ushort* g, ushort* l) {
    __builtin_amdgcn_global_load_lds((gas_t*)g, (las_t*)l, 16, 0, 0);
}

// XCD-chunked swizzle (grid total must be %8==0)
__device__ inline int swz_orig_2d() {
    const int n   = blockIdx.y * gridDim.x + blockIdx.x;
    const int tot = gridDim.x * gridDim.y;
    return (n & 7) * (tot >> 3) + (n >> 3);
}
__device__ inline int swz_orig_3d() {
    const int n   = (blockIdx.z * gridDim.y + blockIdx.y) * gridDim.x + blockIdx.x;
    const int tot = gridDim.x * gridDim.y * gridDim.z;
    return (n & 7) * (tot >> 3) + (n >> 3);
}

// =========================== prep kernels ===========================
__global__ __launch_bounds__(256)
void tpose_cvt_k(const float* __restrict__ in, ushort* __restrict__ out,
                 int K, int N, size_t inStride, size_t outStride) {
    __shared__ float T[32][33];
    const float* ib = in  + (size_t)blockIdx.z * inStride;
    ushort*      ob = out + (size_t)blockIdx.z * outStride;
    const int k0 = blockIdx.x * 32, n0 = blockIdx.y * 32;
    const int tx = threadIdx.x & 31, ty = threadIdx.x >> 5;
#pragma unroll
    for (int i = 0; i < 4; ++i) T[ty + 8 * i][tx] = ib[(size_t)(k0 + ty + 8 * i) * N + n0 + tx];
    __syncthreads();
#pragma unroll
    for (int i = 0; i < 4; ++i)
        ob[(size_t)(n0 + ty + 8 * i) * K + k0 + tx] = f2b(T[tx][ty + 8 * i]);
}

// Wp fold: diff segment absorbed -> WpT'[n][k'] over K'=6144
__global__ __launch_bounds__(256)
void tpose_wp_k(const float* __restrict__ Wp, ushort* __restrict__ out) {
    __shared__ float T[32][33];
    const int k0 = blockIdx.x * 32, n0 = blockIdx.y * 32;
    const int tx = threadIdx.x & 31, ty = threadIdx.x >> 5;
#pragma unroll
    for (int i = 0; i < 4; ++i) {
        const int k = k0 + ty + 8 * i, n = n0 + tx;
        float v = Wp[(size_t)k * HH + n];
        if (k < DD)           v += Wp[(size_t)(k + 6 * DD) * HH + n];
        else if (k < 2 * DD)  v -= Wp[(size_t)(k + 5 * DD) * HH + n];
        T[ty + 8 * i][tx] = v;
    }
    __syncthreads();
#pragma unroll
    for (int i = 0; i < 4; ++i)
        out[(size_t)(n0 + ty + 8 * i) * KOUT6 + k0 + tx] = f2b(T[tx][ty + 8 * i]);
}

// merged: XbE row-major copy + per-batch transpose (PbT/HbT), one read of P/H
__global__ __launch_bounds__(256)
void prep_xt_k(const float* __restrict__ P, const float* __restrict__ H,
               ushort* __restrict__ XbE, ushort* __restrict__ PbT,
               ushort* __restrict__ HbT) {
    __shared__ float T[32][33];
    const int z = blockIdx.z;                 // 0..63: side*32 + b
    const int side = z >> 5, b = z & 31;
    const float* in = (side ? H : P) + (size_t)b * SS * DD;
    ushort* xe = XbE + ((size_t)side * NROW + (size_t)b * SS) * DD;
    ushort* xt = (side ? HbT : PbT) + (size_t)b * DD * SS;
    const int d0 = blockIdx.x * 32, s0 = blockIdx.y * 32;
    const int tx = threadIdx.x & 31, ty = threadIdx.x >> 5;
#pragma unroll
    for (int i = 0; i < 4; ++i) {
        const int s = s0 + ty + 8 * i;
        const float v = in[(size_t)s * DD + d0 + tx];
        T[ty + 8 * i][tx] = v;
        xe[(size_t)s * DD + d0 + tx] = f2b(v);
    }
    __syncthreads();
#pragma unroll
    for (int i = 0; i < 4; ++i)
        xt[(size_t)(d0 + ty + 8 * i) * SS + s0 + tx] = f2b(T[tx][ty + 8 * i]);
}

// post-lin prep: Xb = bf16(x), prodb = bf16(x*att)   (alias dead catb region)
__global__ __launch_bounds__(256)
void prep_xprod_k(const float* __restrict__ P, const float* __restrict__ H,
                  const ushort* __restrict__ attAb,
                  ushort* __restrict__ Xb, ushort* __restrict__ prodb) {
    const int idx = blockIdx.x * 256 + threadIdx.x;
    const int row = idx >> 7, chunk = idx & 127;
    const size_t off = (size_t)row * DD + chunk * 8;
    const float* X = (row < NROW) ? (P + off) : (H + off - (size_t)NROW * DD);
    const float4 x0 = ld4(X), x1 = ld4(X + 4);
    float xv[8] = {x0.x, x0.y, x0.z, x0.w, x1.x, x1.y, x1.z, x1.w};
    float av[8];
    b2f8(*(const bf16x8*)&attAb[off], av);
    float pv[8];
#pragma unroll
    for (int j = 0; j < 8; ++j) pv[j] = xv[j] * av[j];
    *(bf16x8*)&Xb[off]    = cvt8(xv);
    *(bf16x8*)&prodb[off] = cvt8(pv);
}

// final reduce (split path): out = relu(out + p1 + bias)
__global__ __launch_bounds__(256)
void reduce_out_k(float* __restrict__ out, const float* __restrict__ p1,
                  const float* __restrict__ bp) {
    const int gid = blockIdx.x * 256 + threadIdx.x;
    const size_t o = (size_t)gid * 4;
    const float4 a = ld4(&out[o]);
    const float4 b = ld4(&p1[o]);
    const float4 bv = ld4(&bp[(int)(o & 511)]);
    *(float4*)&out[o] = make_float4(fmaxf(a.x + b.x + bv.x, 0.f),
                                    fmaxf(a.y + b.y + bv.y, 0.f),
                                    fmaxf(a.z + b.z + bv.z, 0.f),
                                    fmaxf(a.w + b.w + bv.w, 0.f));
}

// ======= softmax (bf16 in-place, wave-per-row) + fused colsum via atomics =======
// colsum dst mapping (impS/impI must be pre-zeroed):
//   job0 simPH -> impI+NROW | job1 simPHT -> impI | job2 simPP -> impS | job3 simHH -> impS+NROW
__global__ __launch_bounds__(256)
void softmax4_k(ushort* __restrict__ simPH, ushort* __restrict__ simPHT,
                ushort* __restrict__ simPP, ushort* __restrict__ simHH,
                const int* __restrict__ pma, const int* __restrict__ hma,
                float* __restrict__ impS, float* __restrict__ impI) {
    const int job = blockIdx.y;
    ushort* buf = job == 0 ? simPH : job == 1 ? simPHT : job == 2 ? simPP : simHH;
    const int* mask = job == 0 ? hma : job == 1 ? pma : nullptr;
    float* dst = job == 0 ? impI + NROW : job == 1 ? impI : job == 2 ? impS : impS + NROW;
    __shared__ float red[4][256];
    const int w = threadIdx.x >> 6, lane = threadIdx.x & 63;
    const int row = blockIdx.x * 4 + w;            // 4 rows, same batch
    const int b = row >> 8;
    ushort* rp = buf + (size_t)row * SS + lane * 4;
    ushort4 u = *(const ushort4*)rp;
    float z[4], mj[4];
    const ushort uv[4] = {u.x, u.y, u.z, u.w};
#pragma unroll
    for (int c = 0; c < 4; ++c) {
        const float v = b2f(uv[c]);
        float m = 1.f;
        if (mask) m = (float)mask[b * SS + lane * 4 + c];
        mj[c] = m; z[c] = v * m;
    }
    float M = fmaxf(fmaxf(z[0], z[1]), fmaxf(z[2], z[3]));
#pragma unroll
    for (int off = 1; off < 64; off <<= 1) M = fmaxf(M, __shfl_xor(M, off));
    float e[4], r[4], sz = 0.f, sr = 0.f;
#pragma unroll
    for (int c = 0; c < 4; ++c) {
        e[c] = expf(z[c] - M);
        r[c] = e[c] * mj[c];
        sz += e[c]; sr += r[c];
    }
#pragma unroll
    for (int off = 1; off < 64; off <<= 1) {
        sz += __shfl_xor(sz, off);
        sr += __shfl_xor(sr, off);
    }
    ushort4 o;
    float p[4];
    if (mask) {
        const float d = 1.f / (sr + EPSF * sz);
#pragma unroll
        for (int c = 0; c < 4; ++c) p[c] = r[c] * d;
    } else {
        const float d = 1.f / sz;
#pragma unroll
        for (int c = 0; c < 4; ++c) p[c] = e[c] * d;
    }
    o.x = f2b(p[0]); o.y = f2b(p[1]); o.z = f2b(p[2]); o.w = f2b(p[3]);
    *(ushort4*)rp = o;
    // column-sum of the bf16-rounded probs (matches what colsum_p1 read before)
    *(float4*)&red[w][lane * 4] =
        make_float4(b2f(o.x), b2f(o.y), b2f(o.z), b2f(o.w));
    __syncthreads();
    const int j = threadIdx.x;                     // 0..255 = column
    const float s4 = red[0][j] + red[1][j] + red[2][j] + red[3][j];
    atomicAdd(&dst[b * SS + j], s4);
}

// =========================== MFMA common ===========================
// regT [4][128][8]: reg-staged path, row XOR LSWZ (2-way free).
// gllT32 [128][32]: GLL BK=32 path (fuse_dual B), sigma swizzle.
// gllT64 [128][64]: GLL BK=64 path: wave w stages rows [32w,32w+32) in 4
//   instrs of 8 rows; 8 lanes cover one row's full 128B line (coalesced);
//   slot = chunk ^ (row&7) -> per-16-lane frag read 2-way (free floor).
#define LSWZ(kg, r) ((r) ^ ((kg) << 1))
#define SIG(r) (((r) >> 1) & 3)
#define FRAG_R(T, r) (*(const bf16x8*)T[kq][LSWZ(kq, r)])
#define FRAG_G(T, r) (*(const bf16x8*)&T[r][(kq ^ SIG(r)) * 8])
#define FRAG_G64(T, r, kh) (*(const bf16x8*)&T[r][((((kh) << 2) + kq) ^ ((r) & 7)) * 8])

#define MFMA_TAIL(afr, bfr, ac)                                                      \
    _Pragma("unroll") for (int m = 0; m < 4; ++m)                                    \
        _Pragma("unroll") for (int n = 0; n < 4; ++n)                                \
            ac[m][n] = __builtin_amdgcn_mfma_f32_16x16x32_bf16(                      \
                afr[m], bfr[n], ac[m][n], 0, 0, 0);

#define MFMA_CORE_G64()                                                              \
    _Pragma("unroll") for (int kh_ = 0; kh_ < 2; ++kh_) {                            \
        bf16x8 afr[4], bfr[4];                                                       \
        _Pragma("unroll") for (int m = 0; m < 4; ++m)                                \
            afr[m] = FRAG_G64(As, wr + m * 16 + fr, kh_);                            \
        _Pragma("unroll") for (int n = 0; n < 4; ++n)                                \
            bfr[n] = FRAG_G64(Bs, wc + n * 16 + fr, kh_);                            \
        MFMA_TAIL(afr, bfr, acc)                                                     \
    }

#define MFMA_PREAMBLE()                                                              \
    const int tid = threadIdx.x;                                                     \
    const int lane = tid & 63;                                                       \
    const int w = tid >> 6;                                                          \
    const int wr = (w >> 1) * 64, wc = (w & 1) * 64;                                 \
    const int fr = lane & 15;                                                        \
    const int kq = lane >> 4;                                                        \
    const int rq = kq * 4;                                                           \
    f32x4 acc[4][4] = {};

// BK=32 gll stage (fuse_dual B only)
#define GLL_STAGE2(seg, pitch, r0, kloc, T)                                          \
    {                                                                                \
        const int rl0_ = w * 32 + (lane >> 2);                                       \
        const int cp_ = lane & 3;                                                    \
        gll16((seg) + (size_t)((r0) + rl0_) * (pitch) + (kloc) + ((cp_ ^ SIG(rl0_)) * 8), \
              &T[w * 32][0]);                                                        \
        const int rl1_ = rl0_ + 16;                                                  \
        gll16((seg) + (size_t)((r0) + rl1_) * (pitch) + (kloc) + ((cp_ ^ SIG(rl1_)) * 8), \
              &T[w * 32 + 16][0]);                                                   \
    }

// BK=64 gll stage: [128][64] tile; 4 instrs/wave, 8 rows each
#define GLL_STAGE64(seg, pitch, r0, kloc, T)                                         \
    {                                                                                \
        _Pragma("unroll")                                                            \
        for (int ii_ = 0; ii_ < 4; ++ii_) {                                          \
            const int rl_ = w * 32 + ii_ * 8 + (lane >> 3);                          \
            const int cp_ = lane & 7;                                                \
            gll16((seg) + (size_t)((r0) + rl_) * (pitch) + (kloc) + (((cp_ ^ (rl_ & 7))) * 8), \
                  &T[w * 32 + ii_ * 8][0]);                                          \
        }                                                                            \
    }

// ---- sim GEMMs (NT, all-gll from bf16 XbE): g0 P@H^T(+T), g1 P@P^T, g2 H@H^T ----
__global__ __launch_bounds__(256)
void mfma_nt_k(const ushort* __restrict__ XbE,
               ushort* __restrict__ simPH, ushort* __restrict__ simPHT,
               ushort* __restrict__ simPP, ushort* __restrict__ simHH) {
    __shared__ __align__(16) ushort As[128][64];
    __shared__ __align__(16) ushort Bs[128][64];
    int orig = swz_orig_3d();                 // grid (2,2,96)
    const int cb = orig & 1; orig >>= 1;
    const int rb = orig & 1; orig >>= 1;
    const int g = orig >> 5, b = orig & 31;
    const ushort* Au = XbE + ((size_t)((g == 2) ? NROW : 0) + (size_t)b * SS) * DD;
    const ushort* Bu = XbE + ((size_t)((g == 1) ? 0 : NROW) + (size_t)b * SS) * DD;
    const int col0 = cb * 128, row0 = rb * 128;
    MFMA_PREAMBLE();
    for (int k0 = 0; k0 < DD; k0 += 64) {
        __syncthreads();
        GLL_STAGE64(Au, DD, row0, k0, As);
        GLL_STAGE64(Bu, DD, col0, k0, Bs);
        __syncthreads();
        MFMA_CORE_G64();
    }
    ushort* Cb = (g == 0 ? simPH : g == 1 ? simPP : simHH) + (size_t)b * SS * SS;
#pragma unroll
    for (int m = 0; m < 4; ++m)
#pragma unroll
        for (int n = 0; n < 4; ++n) {
            const int c = col0 + wc + n * 16 + fr;
            const int r0 = row0 + wr + m * 16 + rq;
#pragma unroll
            for (int r = 0; r < 4; ++r) Cb[(size_t)(r0 + r) * SS + c] = f2b(acc[m][n][r] * SCALE);
            if (g == 0) {
                ushort* Tb = simPHT + (size_t)b * SS * SS;
                ushort4 t;
                t.x = f2b(acc[m][n][0] * SCALE); t.y = f2b(acc[m][n][1] * SCALE);
                t.z = f2b(acc[m][n][2] * SCALE); t.w = f2b(acc[m][n][3] * SCALE);
                *(ushort4*)&Tb[(size_t)c * SS + r0] = t;
            }
        }
}

// ---- att GEMMs (all-gll, BK=64): g0 att_p (mask pm), g1 att_h (mask hm), g2/g3 self ----
__global__ __launch_bounds__(256)
void mfma_att_k(const ushort* __restrict__ ph, const ushort* __restrict__ hp,
                const ushort* __restrict__ spA, const ushort* __restrict__ shA,
                const ushort* __restrict__ PbT, const ushort* __restrict__ HbT,
                const int* __restrict__ pma, const int* __restrict__ hma,
                ushort* __restrict__ attAb, ushort* __restrict__ selfAb) {
    __shared__ __align__(16) ushort As[128][64];
    __shared__ __align__(16) ushort Bs[128][64];
    int orig = swz_orig_3d();                 // grid (8,2,128)
    const int x = orig & 7; orig >>= 3;
    const int y = orig & 1; orig >>= 1;
    const int g = orig >> 5, b = orig & 31;
    const ushort* W  = (g == 0 ? ph : g == 1 ? hp : g == 2 ? spA : shA) + (size_t)b * SS * SS;
    const ushort* BT = ((g == 0 || g == 3) ? HbT : PbT) + (size_t)b * DD * SS;
    const int* rmask = g == 0 ? pma + b * SS : g == 1 ? hma + b * SS : nullptr;
    const int side = (g == 1 || g == 3);
    ushort* Ob = (g < 2 ? attAb : selfAb) + ((size_t)side * NROW + (size_t)b * SS) * DD;
    const int col0 = x * 128, row0 = y * 128;
    MFMA_PREAMBLE();
    for (int k0 = 0; k0 < SS; k0 += 64) {
        __syncthreads();
        GLL_STAGE64(W,  SS, row0, k0, As);
        GLL_STAGE64(BT, SS, col0, k0, Bs);
        __syncthreads();
        MFMA_CORE_G64();
    }
#pragma unroll
    for (int m = 0; m < 4; ++m)
#pragma unroll
        for (int n = 0; n < 4; ++n) {
            const int c = col0 + wc + n * 16 + fr;
#pragma unroll
            for (int r = 0; r < 4; ++r) {
                const int rr = row0 + wr + m * 16 + rq + r;
                const float mm = rmask ? (float)rmask[rr] : 1.0f;
                Ob[(size_t)rr * DD + c] = f2b(acc[m][n][r] * mm);
            }
        }
}

// ---- fuse_pure (BK=64): kf in {0,1,2,4,5,6}; cat = coef[row]*(X@W8_kf) + B8 ----
__global__ __launch_bounds__(256)
void mfma_fuse_pure_k(const ushort* __restrict__ Xb, const float* __restrict__ impS,
                      const float* __restrict__ impI, const ushort* __restrict__ W8T,
                      const float* __restrict__ B8v, ushort* __restrict__ catb) {
    __shared__ __align__(16) ushort As[128][64];
    __shared__ __align__(16) ushort Bs[128][64];
    const int orig = swz_orig_2d();           // grid (12,128)
    const int cb = orig % 12, rb = orig / 12;
    const int kidx = cb >> 1;
    const int kf = kidx + (kidx >= 3 ? 1 : 0);         // 0,1,2,4,5,6
    const int e0 = (cb & 1) * 128, row0 = rb * 128;
    MFMA_PREAMBLE();
    const ushort* Wk = W8T + (size_t)kf * EE * DD;
    for (int k0 = 0; k0 < DD; k0 += 64) {
        __syncthreads();
        GLL_STAGE64(Xb, DD, row0, k0, As);
        GLL_STAGE64(Wk, DD, e0, k0, Bs);
        __syncthreads();
        MFMA_CORE_G64();
    }
#pragma unroll
    for (int m = 0; m < 4; ++m)
#pragma unroll
        for (int n = 0; n < 4; ++n) {
            const int el = e0 + wc + n * 16 + fr;
            const float bv = B8v[kf * EE + el];
#pragma unroll
            for (int r = 0; r < 4; ++r) {
                const int row = row0 + wr + m * 16 + rq + r;
                const float s_ = impS[row], i_ = impI[row];
                float coef;
                switch (kf) {
                    case 0: coef = s_ * i_;             break;
                    case 1: coef = s_ + i_;             break;
                    case 2: coef = fmaxf(s_, i_);       break;
                    case 4: coef = s_ * i_ + 1.f;       break;
                    case 5: coef = s_ + i_ + 1.f;       break;
                    default: coef = fmaxf(s_, i_) + 1.f; break;
                }
                catb[(size_t)row * FDIM + kf * EE + el] = f2b(coef * acc[m][n][r] + bv);
            }
        }
}

// ---- fuse_dual: kf in {3,7}; cat = (smax-smin)*(pos@W) + g(smin)*(X@W) + B8 ----
__global__ __launch_bounds__(256)
void mfma_fuse_dual_k(const ushort* __restrict__ Xb, const float* __restrict__ impS,
                      const float* __restrict__ impI, const ushort* __restrict__ W8T,
                      const float* __restrict__ B8v, ushort* __restrict__ catb) {
    __shared__ __align__(16) ushort AsX[4][128][8];
    __shared__ __align__(16) ushort AsP[4][128][8];
    __shared__ __align__(16) ushort Bs[128][32];
    const int orig = swz_orig_2d();           // grid (4,128)
    const int cb = orig & 3, rb = orig >> 2;
    const int kf = (cb >> 1) ? 7 : 3;
    const int e0 = (cb & 1) * 128, row0 = rb * 128;
    MFMA_PREAMBLE();
    f32x4 accP[4][4] = {};
    const ushort* Wk = W8T + (size_t)kf * EE * DD;
    for (int k0 = 0; k0 < DD; k0 += 32) {
        bf16x8 xr[2], pr[2];
#pragma unroll
        for (int i = 0; i < 2; ++i) {
            const int cid = tid + i * 256, srow = cid >> 2, skc = (cid & 3) * 8;
            xr[i] = *(const bf16x8*)&Xb[(size_t)(row0 + srow) * DD + k0 + skc];
#pragma unroll
            for (int j = 0; j < 8; ++j) {
                const short s = xr[i][j];
                pr[i][j] = (s & (short)0x8000) ? (short)0 : s;
            }
        }
        __syncthreads();
        GLL_STAGE2(Wk, DD, e0, k0, Bs);
#pragma unroll
        for (int i = 0; i < 2; ++i) {
            const int cid = tid + i * 256, kg = cid & 3, rr = LSWZ(kg, cid >> 2);
            *(bf16x8*)AsX[kg][rr] = xr[i];
            *(bf16x8*)AsP[kg][rr] = pr[i];
        }
        __syncthreads();
        {
            bf16x8 ax[4], ap[4], bfr[4];
#pragma unroll
            for (int m = 0; m < 4; ++m) {
                ax[m] = FRAG_R(AsX, wr + m * 16 + fr);
                ap[m] = FRAG_R(AsP, wr + m * 16 + fr);
            }
#pragma unroll
            for (int n = 0; n < 4; ++n) bfr[n] = FRAG_G(Bs, wc + n * 16 + fr);
            MFMA_TAIL(ax, bfr, acc)
            MFMA_TAIL(ap, bfr, accP)
        }
    }
#pragma unroll
    for (int m = 0; m < 4; ++m)
#pragma unroll
        for (int n = 0; n < 4; ++n) {
            const int el = e0 + wc + n * 16 + fr;
            const float bv = B8v[kf * EE + el];
#pragma unroll
            for (int r = 0; r < 4; ++r) {
                const int row = row0 + wr + m * 16 + rq + r;
                const float s_ = impS[row], i_ = impI[row];
                const float smax = fmaxf(s_, i_), smin = fminf(s_, i_);
                const float gg = (kf == 3) ? smin : smin + 1.f;
                catb[(size_t)row * FDIM + kf * EE + el] =
                    f2b((smax - smin) * accP[m][n][r] + gg * acc[m][n][r] + bv);
            }
        }
}

// ---- lin (BK=64): pall = relu(cat @ Wl + bl) ----
__global__ __launch_bounds__(256)
void mfma_lin_k(const ushort* __restrict__ A, const ushort* __restrict__ BT,
                const float* __restrict__ bias, ushort* __restrict__ C) {
    __shared__ __align__(16) ushort As[128][64];
    __shared__ __align__(16) ushort Bs[128][64];
    const int orig = swz_orig_2d();           // grid (16,128)
    const int col0 = (orig & 15) * 128, row0 = (orig >> 4) * 128;
    MFMA_PREAMBLE();
    for (int k0 = 0; k0 < FDIM; k0 += 64) {
        __syncthreads();
        GLL_STAGE64(A,  FDIM, row0, k0, As);
        GLL_STAGE64(BT, FDIM, col0, k0, Bs);
        __syncthreads();
        MFMA_CORE_G64();
    }
#pragma unroll
    for (int m = 0; m < 4; ++m)
#pragma unroll
        for (int n = 0; n < 4; ++n) {
            const int c = col0 + wc + n * 16 + fr;
            const float bv = bias[c];
#pragma unroll
            for (int r = 0; r < 4; ++r) {
                const int rr = row0 + wr + m * 16 + rq + r;
                C[(size_t)rr * FDIM + c] = f2b(fmaxf(acc[m][n][r] + bv, 0.f));
            }
        }
}

// ---- out (BK=64): enh'(K'=6144) @ Wp'; optional K-split across blockIdx.z ----
__device__ inline void out_seg(int k0, const ushort* Xb, const ushort* attAb,
                               const ushort* selfAb, const ushort* pallb,
                               const ushort* prodb,
                               const ushort*& seg, int& pitch, int& kloc) {
    switch (k0 >> 10) {
        case 0:  seg = Xb;     pitch = DD;   kloc = k0;          break;
        case 1:  seg = attAb;  pitch = DD;   kloc = k0 - DD;     break;
        case 2:  seg = selfAb; pitch = DD;   kloc = k0 - 2 * DD; break;
        case 3:
        case 4:  seg = pallb;  pitch = FDIM; kloc = k0 - 3 * DD; break;
        default: seg = prodb;  pitch = DD;   kloc = k0 - 5 * DD; break;
    }
}

__global__ __launch_bounds__(256)
void mfma_out_k(const ushort* __restrict__ Xb, const ushort* __restrict__ attAb,
                const ushort* __restrict__ selfAb, const ushort* __restrict__ pallb,
                const ushort* __restrict__ prodb, const ushort* __restrict__ WpT,
                const float* __restrict__ bp, float* __restrict__ dst0,
                float* __restrict__ dst1, int kchunk, int finalize) {
    __shared__ __align__(16) ushort As[128][64];
    __shared__ __align__(16) ushort Bs[128][64];
    int orig = swz_orig_3d();                 // grid (4,128,z)
    const int x = orig & 3; orig >>= 2;
    const int y = orig & 127; orig >>= 7;
    const int z = orig;
    const int col0 = x * 128, row0 = y * 128;
    const int kbase = z * kchunk;
    float* dst = z == 0 ? dst0 : dst1;
    MFMA_PREAMBLE();
    for (int t = 0; t < kchunk / 64; ++t) {
        const int k0 = kbase + t * 64;
        const ushort* seg; int pitch, kloc;
        out_seg(k0, Xb, attAb, selfAb, pallb, prodb, seg, pitch, kloc);
        __syncthreads();
        GLL_STAGE64(seg, pitch, row0, kloc, As);
        GLL_STAGE64(WpT, KOUT6, col0, k0, Bs);
        __syncthreads();
        MFMA_CORE_G64();
    }
#pragma unroll
    for (int m = 0; m < 4; ++m)
#pragma unroll
        for (int n = 0; n < 4; ++n) {
            const int c = col0 + wc + n * 16 + fr;
            const float bv = finalize ? bp[c] : 0.f;
#pragma unroll
            for (int r = 0; r < 4; ++r) {
                const int rr = row0 + wr + m * 16 + rq + r;
                const float v = acc[m][n][r] + bv;
                dst[(size_t)rr * HH + c] = finalize ? fmaxf(v, 0.f) : v;
            }
        }
}

// =========================== launcher ===========================
// Workspace (proven-safe layout):
//   region0 67.1: [sims 16.8 | PbT/HbT 33.5] -> catb -> [Xb | prodb]
//   att/self 67.1 | pallb 67.1 (XbE squats [0:33.5] pre-lin)
//   weights 18.9 | imp 0.13 | part1 33.6 (split only if ws allows)
extern "C" void kernel_launch(void* const* d_in, const int* in_sizes, int n_in,
                              void* d_out, int out_size, void* d_ws, size_t ws_size,
                              hipStream_t stream) {
    const float* P   = (const float*)d_in[0];
    const float* Hb  = (const float*)d_in[1];
    const int*   pma = (const int*)d_in[2];
    const int*   hma = (const int*)d_in[3];
    const float* W8  = (const float*)d_in[4];
    const float* B8v = (const float*)d_in[5];
    const float* Wl  = (const float*)d_in[6];
    const float* bl  = (const float*)d_in[7];
    const float* Wp  = (const float*)d_in[8];
    const float* bp  = (const float*)d_in[9];

    char* base = (char*)d_ws;
    ushort* simPH  = (ushort*)base;
    ushort* simPHT = simPH  + SIMSZ;
    ushort* simPP  = simPHT + SIMSZ;
    ushort* simHH  = simPP  + SIMSZ;
    ushort* PbT    = simHH + SIMSZ;
    ushort* HbT    = PbT + (size_t)NROW * DD;
    ushort* catb   = (ushort*)base;                    // alias of region0
    ushort* Xb     = (ushort*)base;                    // alias (post-lin)
    ushort* prodb  = Xb + (size_t)NROW2 * DD;          // alias (post-lin)
    char* cur = base + (size_t)NROW2 * FDIM * 2;       // fixed 67.1 MB region0
    auto alloc_f = [&](size_t n) { float*  p = (float*)cur;  cur += n * 4; return p; };
    auto alloc_u = [&](size_t n) { ushort* p = (ushort*)cur; cur += n * 2; return p; };
    float*  impS   = alloc_f(NROW2);
    float*  impI   = alloc_f(NROW2);
    ushort* attAb  = alloc_u((size_t)NROW2 * DD);
    ushort* selfAb = alloc_u((size_t)NROW2 * DD);
    ushort* pallb  = alloc_u((size_t)NROW2 * FDIM);
    ushort* WlT    = alloc_u((size_t)FDIM * FDIM);
    ushort* WpT    = alloc_u((size_t)HH * KOUT6);
    ushort* W8T    = alloc_u((size_t)8 * EE * DD);
    float*  part1  = alloc_f((size_t)NROW2 * HH);      // only used if split

    ushort* XbE = pallb;                               // Xb_early squats in pallb

    const size_t need_split = (size_t)((char*)(part1 + (size_t)NROW2 * HH) - base);
    const bool split = ws_size >= need_split;

    float* outp = (float*)d_out;
    const dim3 blk(256);

    // ---- preps (merged X copy + transpose: one read of P/H)
    prep_xt_k<<<dim3(DD / 32, SS / 32, 2 * BB), blk, 0, stream>>>(P, Hb, XbE, PbT, HbT);
    tpose_cvt_k<<<dim3(FDIM / 32, FDIM / 32, 1), blk, 0, stream>>>(Wl, WlT, FDIM, FDIM, 0, 0);
    tpose_wp_k<<<dim3(KOUT6 / 32, HH / 32, 1), blk, 0, stream>>>(Wp, WpT);
    tpose_cvt_k<<<dim3(DD / 32, EE / 32, 8), blk, 0, stream>>>(W8, W8T, DD, EE,
                                                               (size_t)DD * EE, (size_t)EE * DD);

    // ---- attention pipeline (colsum fused into softmax via atomics)
    hipMemsetAsync(impS, 0, (size_t)2 * NROW2 * sizeof(float), stream);
    mfma_nt_k<<<dim3(2, 2, 96), blk, 0, stream>>>(XbE, simPH, simPHT, simPP, simHH);
    softmax4_k<<<dim3(NROW / 4, 4), blk, 0, stream>>>(simPH, simPHT, simPP, simHH,
                                                      pma, hma, impS, impI);
    mfma_att_k<<<dim3(8, 2, 128), blk, 0, stream>>>(simPH, simPHT, simPP, simHH, PbT, HbT,
                                                    pma, hma, attAb, selfAb);

    // ---- fused projection pipeline
    mfma_fuse_pure_k<<<dim3(12, 128), blk, 0, stream>>>(XbE, impS, impI, W8T, B8v, catb);
    mfma_fuse_dual_k<<<dim3(4, 128), blk, 0, stream>>>(XbE, impS, impI, W8T, B8v, catb);
    mfma_lin_k<<<dim3(16, 128), blk, 0, stream>>>(catb, WlT, bl, pallb);
    prep_xprod_k<<<dim3(NROW2 * DD / 8 / 256), blk, 0, stream>>>(P, Hb, attAb, Xb, prodb);
    if (split) {
        mfma_out_k<<<dim3(4, 128, 2), blk, 0, stream>>>(Xb, attAb, selfAb, pallb, prodb,
                                                        WpT, bp, outp, part1, KOUT6 / 2, 0);
        reduce_out_k<<<dim3(NROW2 * HH / 4 / 256), blk, 0, stream>>>(outp, part1, bp);
    } else {
        mfma_out_k<<<dim3(4, 128, 1), blk, 0, stream>>>(Xb, attAb, selfAb, pallb, prodb,
                                                        WpT, bp, outp, outp, KOUT6, 1);
    }

    (void)in_sizes; (void)n_in; (void)out_size; (void)ws_size;
}